// Round 4
// baseline (341.344 us; speedup 1.0000x reference)
//
#include <hip/hip_runtime.h>
#include <hip/hip_bf16.h>

#define NN 32768      // nodes
#define NE 131072     // edges
#define HH 4          // heads

constexpr float kLrelu = 0.2f;

using bf16x8 = __attribute__((ext_vector_type(8))) __bf16;
using f32x4  = __attribute__((ext_vector_type(4))) float;

__device__ inline short f2b(float f) {
    __hip_bfloat16 h = __float2bfloat16(f);          // RTNE
    return __builtin_bit_cast(short, h);
}
__device__ inline float b2f(short s) {
    __hip_bfloat16 h = __builtin_bit_cast(__hip_bfloat16, s);
    return __bfloat162float(h);
}

// ---------------------------------------------------------------------------
// LDS-staged bf16 MFMA GEMM: C[M,OUTN] = A[M,K](bf16, row stride LDA) @ Wt^T.
// Wt is [OUTN,K] bf16. Tile BM x BN, 4 waves. A/B staged to LDS with +8-short
// row padding (KP): stride/4 = 4*odd dwords -> conflict-free ds_read_b128.
// Staging loads are coalesced 16B/lane streams (tile rows contiguous).
// Wave (wm,wn): rows wm*32 (2 frags), cols wn*(BN/WN) (CF frags).
// C/D layout (m89-verified): row=(lane>>4)*4+j, col=lane&15.
// SCORES: fused f32 partial dots with a_src/a_trg; head h=(frag col)/FH
// (valid: FH%16==0 so each 16-col frag lies in one head).
// ---------------------------------------------------------------------------
template<int K, int LDA, int OUTN, int BM, int BN, bool BF16OUT, bool SCORES, int FH>
__global__ __launch_bounds__(256) void mfma_gemm(
    const short* __restrict__ A, const short* __restrict__ Wt,
    const float* __restrict__ bias,
    float* __restrict__ Cf, short* __restrict__ Cb,
    const float* __restrict__ a_src, const float* __restrict__ a_trg,
    float* __restrict__ ssrc, float* __restrict__ strg)
{
    constexpr int KP   = K + 8;           // padded row (shorts)
    constexpr int WM   = BM / 32;         // waves along rows
    constexpr int WN   = 4 / WM;          // waves along cols
    constexpr int WBN  = BN / WN;         // cols per wave
    constexpr int CF   = WBN / 16;        // col frags per wave
    constexpr int CPR  = K / 8;           // 16B chunks per row

    __shared__ short As[BM * KP];
    __shared__ short Bs[BN * KP];

    const int tid  = threadIdx.x;
    const int wave = tid >> 6;
    const int lane = tid & 63;
    const int lr   = lane & 15;
    const int kb   = lane >> 4;           // 0..3
    const int wm   = wave % WM;
    const int wn   = wave / WM;
    const int row0 = blockIdx.x * BM;
    const int col0 = blockIdx.y * BN;

    // ---- stage A tile (coalesced 16B chunks) ----
    #pragma unroll
    for (int g = tid; g < BM * CPR; g += 256) {
        int r = g / CPR, c = g - r * CPR;
        bf16x8 v = *(const bf16x8*)(A + (size_t)(row0 + r) * LDA + c * 8);
        *(bf16x8*)(As + r * KP + c * 8) = v;
    }
    // ---- stage B tile ----
    #pragma unroll
    for (int g = tid; g < BN * CPR; g += 256) {
        int r = g / CPR, c = g - r * CPR;
        bf16x8 v = *(const bf16x8*)(Wt + (size_t)(col0 + r) * K + c * 8);
        *(bf16x8*)(Bs + r * KP + c * 8) = v;
    }
    __syncthreads();

    // ---- MFMA K-loop from LDS ----
    f32x4 acc[2][CF] = {};
    #pragma unroll
    for (int k0 = 0; k0 < K; k0 += 32) {
        bf16x8 af0 = *(const bf16x8*)(As + (wm * 32 + lr     ) * KP + k0 + kb * 8);
        bf16x8 af1 = *(const bf16x8*)(As + (wm * 32 + lr + 16) * KP + k0 + kb * 8);
        #pragma unroll
        for (int cf = 0; cf < CF; ++cf) {
            bf16x8 bv = *(const bf16x8*)(Bs + (wn * WBN + cf * 16 + lr) * KP + k0 + kb * 8);
            acc[0][cf] = __builtin_amdgcn_mfma_f32_16x16x32_bf16(af0, bv, acc[0][cf], 0, 0, 0);
            acc[1][cf] = __builtin_amdgcn_mfma_f32_16x16x32_bf16(af1, bv, acc[1][cf], 0, 0, 0);
        }
    }

    // ---- C write (rows of a block cover contiguous BN cols) ----
    #pragma unroll
    for (int mf = 0; mf < 2; ++mf) {
        #pragma unroll
        for (int cf = 0; cf < CF; ++cf) {
            const int c  = col0 + wn * WBN + cf * 16 + lr;
            const float bv = bias ? bias[c] : 0.0f;
            #pragma unroll
            for (int j = 0; j < 4; ++j) {
                const int r = row0 + wm * 32 + mf * 16 + kb * 4 + j;
                const float v = acc[mf][cf][j] + bv;
                if constexpr (BF16OUT) Cb[(size_t)r * OUTN + c] = f2b(v);
                else                   Cf[(size_t)r * OUTN + c] = v;
            }
        }
    }

    // ---- fused attention-score partials (f32 precision) ----
    if constexpr (SCORES) {
        #pragma unroll
        for (int cf = 0; cf < CF; ++cf) {
            const int gcb = col0 + wn * WBN + cf * 16;   // frag col base
            const int h   = gcb / FH;                    // frag-uniform head
            const float as = a_src[gcb + lr];            // flat [H*FH] == col index
            const float at = a_trg[gcb + lr];
            #pragma unroll
            for (int mf = 0; mf < 2; ++mf) {
                #pragma unroll
                for (int j = 0; j < 4; ++j) {
                    float ps = acc[mf][cf][j] * as;
                    float pt = acc[mf][cf][j] * at;
                    #pragma unroll
                    for (int m = 1; m < 16; m <<= 1) {
                        ps += __shfl_xor(ps, m);
                        pt += __shfl_xor(pt, m);
                    }
                    if (lr == 0) {
                        const int r = row0 + wm * 32 + mf * 16 + kb * 4 + j;
                        atomicAdd(&ssrc[r * HH + h], ps);
                        atomicAdd(&strg[r * HH + h], pt);
                    }
                }
            }
        }
    }
}

// ---------------------------------------------------------------------------
// All 6 weight transposes (fp32 -> bf16, [K,N] -> [N,K]) in one launch.
// ---------------------------------------------------------------------------
__global__ __launch_bounds__(256) void wt_all_kernel(
    const float* W0, const float* W1, const float* W2,
    const float* W3, const float* W4, const float* W5,
    short* T0, short* T1, short* T2, short* T3, short* T4, short* T5)
{
    int K, N; const float* W; short* T;
    switch (blockIdx.y) {
        case 0: K = 128; N =  64; W = W0; T = T0; break;
        case 1: K =  64; N = 256; W = W1; T = T1; break;
        case 2: K =  64; N = 128; W = W2; T = T2; break;
        case 3: K = 160; N =  96; W = W3; T = T3; break;
        case 4: K =  96; N = 384; W = W4; T = T4; break;
        default:K =  96; N = 160; W = W5; T = T5; break;
    }
    int t = blockIdx.x * 256 + threadIdx.x;
    if (t >= K * N) return;
    int n = t / K, k = t - n * K;
    T[t] = f2b(W[(size_t)k * N + n]);
}

// ---------------------------------------------------------------------------
// Build bf16 concat [N,160] = [rna | prot]
// ---------------------------------------------------------------------------
__global__ __launch_bounds__(256) void concat_kernel(
    const float* __restrict__ rna, const float* __restrict__ prot,
    short* __restrict__ cb)
{
    int t = blockIdx.x * 256 + threadIdx.x;
    if (t >= NN * 40) return;
    int n = t / 40, j = (t - n * 40) * 4;
    float4 v = (j < 128) ? *(const float4*)(rna  + (size_t)n * 128 + j)
                         : *(const float4*)(prot + (size_t)n * 32 + (j - 128));
    short4 o = { f2b(v.x), f2b(v.y), f2b(v.z), f2b(v.w) };
    *(short4*)(cb + (size_t)n * 160 + j) = o;
}

// ---------------------------------------------------------------------------
// CSR build (grouped by trg, shared by both paths)
// ---------------------------------------------------------------------------
__global__ __launch_bounds__(256) void hist_kernel(const int* __restrict__ ei,
                                                   int* __restrict__ deg)
{
    int e = blockIdx.x * 256 + threadIdx.x;
    if (e < NE) atomicAdd(&deg[ei[NE + e]], 1);
}

__global__ __launch_bounds__(1024) void scan_kernel(const int* __restrict__ deg,
                                                    int* __restrict__ rowptr,
                                                    int* __restrict__ cursor)
{
    __shared__ int sums[1024];
    const int t = threadIdx.x;
    const int base = t * 32;
    int local[32];
    int s = 0;
    #pragma unroll
    for (int i = 0; i < 32; ++i) { local[i] = s; s += deg[base + i]; }
    sums[t] = s;
    __syncthreads();
    for (int off = 1; off < 1024; off <<= 1) {
        int v = (t >= off) ? sums[t - off] : 0;
        __syncthreads();
        sums[t] += v;
        __syncthreads();
    }
    const int prev = (t == 0) ? 0 : sums[t - 1];
    #pragma unroll
    for (int i = 0; i < 32; ++i) {
        rowptr[base + i] = prev + local[i];
        cursor[base + i] = prev + local[i];
    }
    if (t == 1023) rowptr[NN] = prev + s;
}

__global__ __launch_bounds__(256) void scatter_kernel(
    const int* __restrict__ ei, int* __restrict__ cursor,
    int* __restrict__ csr_src, int* __restrict__ csr_e)
{
    int e = blockIdx.x * 256 + threadIdx.x;
    if (e >= NE) return;
    int s = ei[e], t = ei[NE + e];
    int slot = atomicAdd(&cursor[t], 1);
    csr_src[slot] = s;
    csr_e[slot]   = e;
}

// ---------------------------------------------------------------------------
// Per-edge exp(lrelu(score)); denom atomics only for the src-grouped path.
// ---------------------------------------------------------------------------
template<bool DENOM>
__global__ __launch_bounds__(256) void edge_kernel(
    const int* __restrict__ ei,
    const float* __restrict__ s_src, const float* __restrict__ s_trg,
    float* __restrict__ ex, float* __restrict__ denom)
{
    int e = blockIdx.x * 256 + threadIdx.x;
    if (e >= NE) return;
    int s = ei[e], t = ei[NE + e];
    const float4 ss = *(const float4*)(s_src + 4 * (size_t)s);
    const float4 st = *(const float4*)(s_trg + 4 * (size_t)t);
    float sc[4] = { ss.x + st.x, ss.y + st.y, ss.z + st.z, ss.w + st.w };
    float ev[4];
    #pragma unroll
    for (int h = 0; h < 4; ++h) {
        float x  = sc[h];
        float lr = x > 0.f ? x : kLrelu * x;
        ev[h] = expf(lr);
        if constexpr (DENOM) atomicAdd(&denom[4 * (size_t)s + h], ev[h]);
    }
    *(float4*)(ex + 4 * (size_t)e) = make_float4(ev[0], ev[1], ev[2], ev[3]);
}

// ---------------------------------------------------------------------------
// CSR aggregation, atomic-free output, fused mean+skip+bias -> bf16.
// GROUP_SRC=false (GAT): softmax group == trg -> denominator in-kernel.
// GROUP_SRC=true (cross): denominators gathered from den[src].
// ---------------------------------------------------------------------------
template<int F, int NPB, bool GROUP_SRC>
__global__ __launch_bounds__(F * NPB) void aggregate_csr(
    const int* __restrict__ rowptr, const int* __restrict__ csr_src,
    const int* __restrict__ csr_e,
    const short* __restrict__ proj_b, const float* __restrict__ ex,
    const float* __restrict__ den,
    const short* __restrict__ x_pb, const float* __restrict__ bias,
    short* __restrict__ aggb)
{
    const int f    = threadIdx.x;
    const int node = blockIdx.x * NPB + threadIdx.y;
    const int beg  = rowptr[node], end = rowptr[node + 1];
    float acc = 0.f;

    if constexpr (!GROUP_SRC) {
        float d0 = 0.f, d1 = 0.f, d2 = 0.f, d3 = 0.f;
        for (int sl = beg; sl < end; ++sl) {
            const float4 ev = *(const float4*)(ex + 4 * (size_t)csr_e[sl]);
            d0 += ev.x; d1 += ev.y; d2 += ev.z; d3 += ev.w;
        }
        const float r0 = 1.f / (d0 + 1e-16f), r1 = 1.f / (d1 + 1e-16f);
        const float r2 = 1.f / (d2 + 1e-16f), r3 = 1.f / (d3 + 1e-16f);
        for (int sl = beg; sl < end; ++sl) {
            const int s = csr_src[sl];
            const float4 ev = *(const float4*)(ex + 4 * (size_t)csr_e[sl]);
            const short* p = proj_b + (size_t)s * (4 * F) + f;
            acc += b2f(p[0])     * (ev.x * r0) + b2f(p[F])     * (ev.y * r1)
                 + b2f(p[2 * F]) * (ev.z * r2) + b2f(p[3 * F]) * (ev.w * r3);
        }
    } else {
        for (int sl = beg; sl < end; ++sl) {
            const int s = csr_src[sl];
            const float4 ev = *(const float4*)(ex  + 4 * (size_t)csr_e[sl]);
            const float4 dv = *(const float4*)(den + 4 * (size_t)s);
            const short* p = proj_b + (size_t)s * (4 * F) + f;
            acc += b2f(p[0])     * (ev.x / (dv.x + 1e-16f))
                 + b2f(p[F])     * (ev.y / (dv.y + 1e-16f))
                 + b2f(p[2 * F]) * (ev.z / (dv.z + 1e-16f))
                 + b2f(p[3 * F]) * (ev.w / (dv.w + 1e-16f));
        }
    }
    const int o = node * F + f;
    aggb[o] = f2b(acc * 0.25f + b2f(x_pb[o]) + bias[f]);
}

// ---------------------------------------------------------------------------
extern "C" void kernel_launch(void* const* d_in, const int* in_sizes, int n_in,
                              void* d_out, int out_size, void* d_ws, size_t ws_size,
                              hipStream_t stream)
{
    const float* rna   = (const float*)d_in[0];    // [N,128]
    const float* prot  = (const float*)d_in[1];    // [N,32]
    const int*   ei    = (const int*)  d_in[2];    // [2,E]
    const float* Wgp   = (const float*)d_in[3];    // [128,64]
    const float* bgp   = (const float*)d_in[4];
    const float* Wgr   = (const float*)d_in[5];    // [64,128]
    const float* bgr   = (const float*)d_in[6];
    const float* Wg    = (const float*)d_in[7];    // [64,256]
    const float* ags   = (const float*)d_in[8];    // [4,64]
    const float* agt   = (const float*)d_in[9];
    const float* bg    = (const float*)d_in[10];   // [64]
    const float* Wcp   = (const float*)d_in[11];   // [160,96]
    const float* bcp   = (const float*)d_in[12];
    const float* Wcr   = (const float*)d_in[13];   // [96,160]
    const float* bcr   = (const float*)d_in[14];
    const float* Wc    = (const float*)d_in[15];   // [96,384]
    const float* acs   = (const float*)d_in[16];   // [4,96]
    const float* act   = (const float*)d_in[17];
    const float* bc    = (const float*)d_in[18];   // [96]

    float* out_gat   = (float*)d_out;              // [N,128]
    float* out_cross = out_gat + (size_t)NN * 128; // [N,160]

    // ---- workspace layout ----
    float* ex    = (float*)d_ws;                   // E*4 f32
    float* ssrc  = ex   + (size_t)NE * 4;          // N*4 f32
    float* strg  = ssrc + (size_t)NN * 4;          // N*4 f32
    float* den   = strg + (size_t)NN * 4;          // N*4 f32
    short* proj_b = (short*)(den + (size_t)NN * 4);// N*384 bf16
    short* cb    = proj_b + (size_t)NN * 384;      // N*160 bf16
    short* x_pb  = cb    + (size_t)NN * 160;       // N*96 bf16
    short* aggb  = x_pb  + (size_t)NN * 96;        // N*96 bf16
    short* wt_gp = aggb  + (size_t)NN * 96;        // [64,128]
    short* wt_g  = wt_gp + 128 * 64;               // [256,64]
    short* wt_gr = wt_g  + 64 * 256;               // [128,64]
    short* wt_cp = wt_gr + 64 * 128;               // [96,160]
    short* wt_c  = wt_cp + 160 * 96;               // [384,96]
    short* wt_cr = wt_c  + 96 * 384;               // [160,96]
    int*   deg   = (int*)(wt_cr + 96 * 160);       // N
    int*   cursor= deg    + NN;                    // N
    int*   rowptr= cursor + NN;                    // N+1
    int*   csr_src = rowptr + NN + 1;              // E
    int*   csr_e   = csr_src + NE;                 // E

    // ---- one-time converts + CSR build (shared by both paths) ----
    concat_kernel<<<(NN * 40 + 255) / 256, 256, 0, stream>>>(rna, prot, cb);
    wt_all_kernel<<<dim3(144, 6), 256, 0, stream>>>(Wgp, Wg, Wgr, Wcp, Wc, Wcr,
                                                    wt_gp, wt_g, wt_gr, wt_cp, wt_c, wt_cr);
    hipMemsetAsync(deg, 0, (size_t)NN * sizeof(int), stream);
    hist_kernel<<<NE / 256, 256, 0, stream>>>(ei, deg);
    scan_kernel<<<1, 1024, 0, stream>>>(deg, rowptr, cursor);
    scatter_kernel<<<NE / 256, 256, 0, stream>>>(ei, cursor, csr_src, csr_e);

    // ======================= GAT path (F=64, softmax on trg) ================
    hipMemsetAsync(ssrc, 0, (size_t)NN * 12 * sizeof(float), stream);  // ssrc+strg+den
    mfma_gemm<128, 160,  64, 128,  64, true , false,  64><<<dim3(256, 1), 256, 0, stream>>>(
        cb, wt_gp, bgp, nullptr, x_pb, nullptr, nullptr, nullptr, nullptr);
    mfma_gemm< 64,  64, 256, 128, 128, true , true ,  64><<<dim3(256, 2), 256, 0, stream>>>(
        x_pb, wt_g, nullptr, nullptr, proj_b, ags, agt, ssrc, strg);
    edge_kernel<false><<<NE / 256, 256, 0, stream>>>(ei, ssrc, strg, ex, den);
    aggregate_csr<64, 4, false><<<NN / 4, dim3(64, 4), 0, stream>>>(
        rowptr, csr_src, csr_e, proj_b, ex, nullptr, x_pb, bg, aggb);
    mfma_gemm< 64,  64, 128, 128, 128, false, false,  64><<<dim3(256, 1), 256, 0, stream>>>(
        aggb, wt_gr, bgr, out_gat, nullptr, nullptr, nullptr, nullptr, nullptr);

    // ====================== Cross path (F=96, softmax on src) ===============
    hipMemsetAsync(ssrc, 0, (size_t)NN * 12 * sizeof(float), stream);  // ssrc+strg+den
    mfma_gemm<160, 160,  96,  64,  96, true , false,  96><<<dim3(512, 1), 256, 0, stream>>>(
        cb, wt_cp, bcp, nullptr, x_pb, nullptr, nullptr, nullptr, nullptr);
    mfma_gemm< 96,  96, 384, 128, 128, true , true ,  96><<<dim3(256, 3), 256, 0, stream>>>(
        x_pb, wt_c, nullptr, nullptr, proj_b, acs, act, ssrc, strg);
    edge_kernel<true><<<NE / 256, 256, 0, stream>>>(ei, ssrc, strg, ex, den);
    aggregate_csr<96, 2, true><<<NN / 2, dim3(96, 2), 0, stream>>>(
        rowptr, csr_src, csr_e, proj_b, ex, den, x_pb, bc, aggb);
    mfma_gemm< 96,  96, 160, 128,  80, false, false,  96><<<dim3(256, 2), 256, 0, stream>>>(
        aggb, wt_cr, bcr, out_cross, nullptr, nullptr, nullptr, nullptr, nullptr);
}

// Round 5
// 340.664 us; speedup vs baseline: 1.0020x; 1.0020x over previous
//
#include <hip/hip_runtime.h>
#include <hip/hip_bf16.h>

#define NN 32768      // nodes
#define NE 131072     // edges
#define HH 4          // heads

constexpr float kLrelu = 0.2f;

using bf16x8 = __attribute__((ext_vector_type(8))) __bf16;
using f32x4  = __attribute__((ext_vector_type(4))) float;

__device__ inline short f2b(float f) {
    __hip_bfloat16 h = __float2bfloat16(f);          // RTNE
    return __builtin_bit_cast(short, h);
}
__device__ inline float b2f(short s) {
    __hip_bfloat16 h = __builtin_bit_cast(__hip_bfloat16, s);
    return __bfloat162float(h);
}

// ---------------------------------------------------------------------------
// LDS-staged bf16 MFMA GEMM: C[M,OUTN] = A[M,K](bf16, row stride LDA) @ Wt^T.
// Wt is [OUTN,K] bf16. Tile BM x BN, 4 waves (WM x WN). A/B staged to LDS
// with +8-short row pad (stride/4 = 4*odd dwords -> <=4-way ds conflicts).
// Staging loads are coalesced 16B/lane streams (tile rows contiguous).
// C/D frag layout (m89-verified): row=(lane>>4)*4+j, col=lane&15.
// EPILOGUE: acc -> per-wave LDS slice (reusing As/Bs) -> coalesced 16B/lane
// global stores (fixes the 2-3x HBM write amplification of scalar stores).
// SCORES: fused f32 partial dots with a_src/a_trg (head = frag col / FH).
// ---------------------------------------------------------------------------
template<int K, int LDA, int OUTN, int BM, int BN, bool BF16OUT, bool SCORES, int FH>
__global__ __launch_bounds__(256) void mfma_gemm(
    const short* __restrict__ A, const short* __restrict__ Wt,
    const float* __restrict__ bias,
    float* __restrict__ Cf, short* __restrict__ Cb,
    const float* __restrict__ a_src, const float* __restrict__ a_trg,
    float* __restrict__ ssrc, float* __restrict__ strg)
{
    constexpr int KP    = K + 8;           // padded LDS row (shorts)
    constexpr int WM    = BM / 32;         // waves along rows
    constexpr int WN    = 4 / WM;          // waves along cols
    constexpr int WBN   = BN / WN;         // cols per wave
    constexpr int CF    = WBN / 16;        // col frags per wave
    constexpr int CPR   = K / 8;           // 16B chunks per K-row
    constexpr int TOT   = (BM + BN) * KP;  // total LDS shorts
    constexpr int SLICE = TOT / 4;         // per-wave epilogue slice (shorts)

    __shared__ short lds[TOT];
    short* As = lds;
    short* Bs = lds + BM * KP;

    const int tid  = threadIdx.x;
    const int wave = tid >> 6;
    const int lane = tid & 63;
    const int lr   = lane & 15;
    const int kb   = lane >> 4;            // 0..3
    const int wm   = wave % WM;
    const int wn   = wave / WM;
    const int row0 = blockIdx.x * BM;
    const int col0 = blockIdx.y * BN;

    // ---- stage A tile (coalesced 16B chunks) ----
    #pragma unroll
    for (int g = tid; g < BM * CPR; g += 256) {
        int r = g / CPR, c = g - r * CPR;
        bf16x8 v = *(const bf16x8*)(A + (size_t)(row0 + r) * LDA + c * 8);
        *(bf16x8*)(As + r * KP + c * 8) = v;
    }
    // ---- stage B tile ----
    #pragma unroll
    for (int g = tid; g < BN * CPR; g += 256) {
        int r = g / CPR, c = g - r * CPR;
        bf16x8 v = *(const bf16x8*)(Wt + (size_t)(col0 + r) * K + c * 8);
        *(bf16x8*)(Bs + r * KP + c * 8) = v;
    }
    __syncthreads();

    // ---- MFMA K-loop from LDS ----
    f32x4 acc[2][CF] = {};
    #pragma unroll
    for (int k0 = 0; k0 < K; k0 += 32) {
        bf16x8 af0 = *(const bf16x8*)(As + (wm * 32 + lr     ) * KP + k0 + kb * 8);
        bf16x8 af1 = *(const bf16x8*)(As + (wm * 32 + lr + 16) * KP + k0 + kb * 8);
        #pragma unroll
        for (int cf = 0; cf < CF; ++cf) {
            bf16x8 bv = *(const bf16x8*)(Bs + (wn * WBN + cf * 16 + lr) * KP + k0 + kb * 8);
            acc[0][cf] = __builtin_amdgcn_mfma_f32_16x16x32_bf16(af0, bv, acc[0][cf], 0, 0, 0);
            acc[1][cf] = __builtin_amdgcn_mfma_f32_16x16x32_bf16(af1, bv, acc[1][cf], 0, 0, 0);
        }
    }

    // ---- fused attention-score partials (reg-only, f32 precision) ----
    if constexpr (SCORES) {
        #pragma unroll
        for (int cf = 0; cf < CF; ++cf) {
            const int gcb = col0 + wn * WBN + cf * 16;   // frag col base
            const int h   = gcb / FH;                    // frag-uniform head
            const float as = a_src[gcb + lr];            // flat [H*FH] == col index
            const float at = a_trg[gcb + lr];
            #pragma unroll
            for (int mf = 0; mf < 2; ++mf) {
                #pragma unroll
                for (int j = 0; j < 4; ++j) {
                    float ps = acc[mf][cf][j] * as;
                    float pt = acc[mf][cf][j] * at;
                    #pragma unroll
                    for (int m = 1; m < 16; m <<= 1) {
                        ps += __shfl_xor(ps, m);
                        pt += __shfl_xor(pt, m);
                    }
                    if (lr == 0) {
                        const int r = row0 + wm * 32 + mf * 16 + kb * 4 + j;
                        atomicAdd(&ssrc[r * HH + h], ps);
                        atomicAdd(&strg[r * HH + h], pt);
                    }
                }
            }
        }
    }

    // ---- coalesced C epilogue via per-wave LDS slice (reuses As/Bs) ----
    #pragma unroll
    for (int mf = 0; mf < 2; ++mf) {
        __syncthreads();   // previous LDS readers (K-loop / prior pass) done
        if constexpr (BF16OUT) {
            constexpr int LEP = WBN + 8;               // shorts per slice row
            short* ep = lds + wave * SLICE;
            #pragma unroll
            for (int cf = 0; cf < CF; ++cf) {
                const int c  = cf * 16 + lr;
                const float bv = bias ? bias[col0 + wn * WBN + c] : 0.0f;
                #pragma unroll
                for (int j = 0; j < 4; ++j)
                    ep[(kb * 4 + j) * LEP + c] = f2b(acc[mf][cf][j] + bv);
            }
            __syncthreads();
            constexpr int CROW = WBN / 8;              // 16B chunks per row
            for (int g = lane; g < 16 * CROW; g += 64) {
                int r = g / CROW, cc = g - r * CROW;
                bf16x8 v = *(const bf16x8*)(ep + r * LEP + cc * 8);
                *(bf16x8*)(Cb + (size_t)(row0 + wm * 32 + mf * 16 + r) * OUTN
                              + col0 + wn * WBN + cc * 8) = v;
            }
        } else {
            constexpr int LEPF = WBN + 4;              // floats per slice row
            float* epf = (float*)(lds + wave * SLICE);
            #pragma unroll
            for (int cf = 0; cf < CF; ++cf) {
                const int c  = cf * 16 + lr;
                const float bv = bias ? bias[col0 + wn * WBN + c] : 0.0f;
                #pragma unroll
                for (int j = 0; j < 4; ++j)
                    epf[(kb * 4 + j) * LEPF + c] = acc[mf][cf][j] + bv;
            }
            __syncthreads();
            constexpr int CROWF = WBN / 4;             // 16B chunks per row
            for (int g = lane; g < 16 * CROWF; g += 64) {
                int r = g / CROWF, cc = g - r * CROWF;
                float4 v = *(const float4*)(epf + r * LEPF + cc * 4);
                *(float4*)(Cf + (size_t)(row0 + wm * 32 + mf * 16 + r) * OUTN
                              + col0 + wn * WBN + cc * 4) = v;
            }
        }
    }
}

// ---------------------------------------------------------------------------
// All 6 weight transposes (fp32 -> bf16, [K,N] -> [N,K]) in one launch.
// ---------------------------------------------------------------------------
__global__ __launch_bounds__(256) void wt_all_kernel(
    const float* W0, const float* W1, const float* W2,
    const float* W3, const float* W4, const float* W5,
    short* T0, short* T1, short* T2, short* T3, short* T4, short* T5)
{
    int K, N; const float* W; short* T;
    switch (blockIdx.y) {
        case 0: K = 128; N =  64; W = W0; T = T0; break;
        case 1: K =  64; N = 256; W = W1; T = T1; break;
        case 2: K =  64; N = 128; W = W2; T = T2; break;
        case 3: K = 160; N =  96; W = W3; T = T3; break;
        case 4: K =  96; N = 384; W = W4; T = T4; break;
        default:K =  96; N = 160; W = W5; T = T5; break;
    }
    int t = blockIdx.x * 256 + threadIdx.x;
    if (t >= K * N) return;
    int n = t / K, k = t - n * K;
    T[t] = f2b(W[(size_t)k * N + n]);
}

// ---------------------------------------------------------------------------
// Build bf16 concat [N,160] = [rna | prot]
// ---------------------------------------------------------------------------
__global__ __launch_bounds__(256) void concat_kernel(
    const float* __restrict__ rna, const float* __restrict__ prot,
    short* __restrict__ cb)
{
    int t = blockIdx.x * 256 + threadIdx.x;
    if (t >= NN * 40) return;
    int n = t / 40, j = (t - n * 40) * 4;
    float4 v = (j < 128) ? *(const float4*)(rna  + (size_t)n * 128 + j)
                         : *(const float4*)(prot + (size_t)n * 32 + (j - 128));
    short4 o = { f2b(v.x), f2b(v.y), f2b(v.z), f2b(v.w) };
    *(short4*)(cb + (size_t)n * 160 + j) = o;
}

// ---------------------------------------------------------------------------
// CSR build (grouped by trg, shared by both paths)
// ---------------------------------------------------------------------------
__global__ __launch_bounds__(256) void hist_kernel(const int* __restrict__ ei,
                                                   int* __restrict__ deg)
{
    int e = blockIdx.x * 256 + threadIdx.x;
    if (e < NE) atomicAdd(&deg[ei[NE + e]], 1);
}

__global__ __launch_bounds__(1024) void scan_kernel(const int* __restrict__ deg,
                                                    int* __restrict__ rowptr,
                                                    int* __restrict__ cursor)
{
    __shared__ int sums[1024];
    const int t = threadIdx.x;
    const int base = t * 32;
    int local[32];
    int s = 0;
    #pragma unroll
    for (int i = 0; i < 32; ++i) { local[i] = s; s += deg[base + i]; }
    sums[t] = s;
    __syncthreads();
    for (int off = 1; off < 1024; off <<= 1) {
        int v = (t >= off) ? sums[t - off] : 0;
        __syncthreads();
        sums[t] += v;
        __syncthreads();
    }
    const int prev = (t == 0) ? 0 : sums[t - 1];
    #pragma unroll
    for (int i = 0; i < 32; ++i) {
        rowptr[base + i] = prev + local[i];
        cursor[base + i] = prev + local[i];
    }
    if (t == 1023) rowptr[NN] = prev + s;
}

__global__ __launch_bounds__(256) void scatter_kernel(
    const int* __restrict__ ei, int* __restrict__ cursor,
    int* __restrict__ csr_src, int* __restrict__ csr_e)
{
    int e = blockIdx.x * 256 + threadIdx.x;
    if (e >= NE) return;
    int s = ei[e], t = ei[NE + e];
    int slot = atomicAdd(&cursor[t], 1);
    csr_src[slot] = s;
    csr_e[slot]   = e;
}

// ---------------------------------------------------------------------------
// Per-edge exp(lrelu(score)); denom atomics only for the src-grouped path.
// ---------------------------------------------------------------------------
template<bool DENOM>
__global__ __launch_bounds__(256) void edge_kernel(
    const int* __restrict__ ei,
    const float* __restrict__ s_src, const float* __restrict__ s_trg,
    float* __restrict__ ex, float* __restrict__ denom)
{
    int e = blockIdx.x * 256 + threadIdx.x;
    if (e >= NE) return;
    int s = ei[e], t = ei[NE + e];
    const float4 ss = *(const float4*)(s_src + 4 * (size_t)s);
    const float4 st = *(const float4*)(s_trg + 4 * (size_t)t);
    float sc[4] = { ss.x + st.x, ss.y + st.y, ss.z + st.z, ss.w + st.w };
    float ev[4];
    #pragma unroll
    for (int h = 0; h < 4; ++h) {
        float x  = sc[h];
        float lr = x > 0.f ? x : kLrelu * x;
        ev[h] = expf(lr);
        if constexpr (DENOM) atomicAdd(&denom[4 * (size_t)s + h], ev[h]);
    }
    *(float4*)(ex + 4 * (size_t)e) = make_float4(ev[0], ev[1], ev[2], ev[3]);
}

// ---------------------------------------------------------------------------
// CSR aggregation, atomic-free output, fused mean+skip+bias -> bf16.
// GROUP_SRC=false (GAT): softmax group == trg -> denominator in-kernel.
// GROUP_SRC=true (cross): denominators gathered from den[src].
// ---------------------------------------------------------------------------
template<int F, int NPB, bool GROUP_SRC>
__global__ __launch_bounds__(F * NPB) void aggregate_csr(
    const int* __restrict__ rowptr, const int* __restrict__ csr_src,
    const int* __restrict__ csr_e,
    const short* __restrict__ proj_b, const float* __restrict__ ex,
    const float* __restrict__ den,
    const short* __restrict__ x_pb, const float* __restrict__ bias,
    short* __restrict__ aggb)
{
    const int f    = threadIdx.x;
    const int node = blockIdx.x * NPB + threadIdx.y;
    const int beg  = rowptr[node], end = rowptr[node + 1];
    float acc = 0.f;

    if constexpr (!GROUP_SRC) {
        float d0 = 0.f, d1 = 0.f, d2 = 0.f, d3 = 0.f;
        for (int sl = beg; sl < end; ++sl) {
            const float4 ev = *(const float4*)(ex + 4 * (size_t)csr_e[sl]);
            d0 += ev.x; d1 += ev.y; d2 += ev.z; d3 += ev.w;
        }
        const float r0 = 1.f / (d0 + 1e-16f), r1 = 1.f / (d1 + 1e-16f);
        const float r2 = 1.f / (d2 + 1e-16f), r3 = 1.f / (d3 + 1e-16f);
        for (int sl = beg; sl < end; ++sl) {
            const int s = csr_src[sl];
            const float4 ev = *(const float4*)(ex + 4 * (size_t)csr_e[sl]);
            const short* p = proj_b + (size_t)s * (4 * F) + f;
            acc += b2f(p[0])     * (ev.x * r0) + b2f(p[F])     * (ev.y * r1)
                 + b2f(p[2 * F]) * (ev.z * r2) + b2f(p[3 * F]) * (ev.w * r3);
        }
    } else {
        for (int sl = beg; sl < end; ++sl) {
            const int s = csr_src[sl];
            const float4 ev = *(const float4*)(ex  + 4 * (size_t)csr_e[sl]);
            const float4 dv = *(const float4*)(den + 4 * (size_t)s);
            const short* p = proj_b + (size_t)s * (4 * F) + f;
            acc += b2f(p[0])     * (ev.x / (dv.x + 1e-16f))
                 + b2f(p[F])     * (ev.y / (dv.y + 1e-16f))
                 + b2f(p[2 * F]) * (ev.z / (dv.z + 1e-16f))
                 + b2f(p[3 * F]) * (ev.w / (dv.w + 1e-16f));
        }
    }
    const int o = node * F + f;
    aggb[o] = f2b(acc * 0.25f + b2f(x_pb[o]) + bias[f]);
}

// ---------------------------------------------------------------------------
extern "C" void kernel_launch(void* const* d_in, const int* in_sizes, int n_in,
                              void* d_out, int out_size, void* d_ws, size_t ws_size,
                              hipStream_t stream)
{
    const float* rna   = (const float*)d_in[0];    // [N,128]
    const float* prot  = (const float*)d_in[1];    // [N,32]
    const int*   ei    = (const int*)  d_in[2];    // [2,E]
    const float* Wgp   = (const float*)d_in[3];    // [128,64]
    const float* bgp   = (const float*)d_in[4];
    const float* Wgr   = (const float*)d_in[5];    // [64,128]
    const float* bgr   = (const float*)d_in[6];
    const float* Wg    = (const float*)d_in[7];    // [64,256]
    const float* ags   = (const float*)d_in[8];    // [4,64]
    const float* agt   = (const float*)d_in[9];
    const float* bg    = (const float*)d_in[10];   // [64]
    const float* Wcp   = (const float*)d_in[11];   // [160,96]
    const float* bcp   = (const float*)d_in[12];
    const float* Wcr   = (const float*)d_in[13];   // [96,160]
    const float* bcr   = (const float*)d_in[14];
    const float* Wc    = (const float*)d_in[15];   // [96,384]
    const float* acs   = (const float*)d_in[16];   // [4,96]
    const float* act   = (const float*)d_in[17];
    const float* bc    = (const float*)d_in[18];   // [96]

    float* out_gat   = (float*)d_out;              // [N,128]
    float* out_cross = out_gat + (size_t)NN * 128; // [N,160]

    // ---- workspace layout ----
    float* ex    = (float*)d_ws;                   // E*4 f32
    float* ssrc  = ex   + (size_t)NE * 4;          // N*4 f32
    float* strg  = ssrc + (size_t)NN * 4;          // N*4 f32
    float* den   = strg + (size_t)NN * 4;          // N*4 f32
    short* proj_b = (short*)(den + (size_t)NN * 4);// N*384 bf16
    short* cb    = proj_b + (size_t)NN * 384;      // N*160 bf16
    short* x_pb  = cb    + (size_t)NN * 160;       // N*96 bf16
    short* aggb  = x_pb  + (size_t)NN * 96;        // N*96 bf16
    short* wt_gp = aggb  + (size_t)NN * 96;        // [64,128]
    short* wt_g  = wt_gp + 128 * 64;               // [256,64]
    short* wt_gr = wt_g  + 64 * 256;               // [128,64]
    short* wt_cp = wt_gr + 64 * 128;               // [96,160]
    short* wt_c  = wt_cp + 160 * 96;               // [384,96]
    short* wt_cr = wt_c  + 96 * 384;               // [160,96]
    int*   deg   = (int*)(wt_cr + 96 * 160);       // N
    int*   cursor= deg    + NN;                    // N
    int*   rowptr= cursor + NN;                    // N+1
    int*   csr_src = rowptr + NN + 1;              // E
    int*   csr_e   = csr_src + NE;                 // E

    // ---- one-time converts + CSR build (shared by both paths) ----
    concat_kernel<<<(NN * 40 + 255) / 256, 256, 0, stream>>>(rna, prot, cb);
    wt_all_kernel<<<dim3(144, 6), 256, 0, stream>>>(Wgp, Wg, Wgr, Wcp, Wc, Wcr,
                                                    wt_gp, wt_g, wt_gr, wt_cp, wt_c, wt_cr);
    hipMemsetAsync(deg, 0, (size_t)NN * sizeof(int), stream);
    hist_kernel<<<NE / 256, 256, 0, stream>>>(ei, deg);
    scan_kernel<<<1, 1024, 0, stream>>>(deg, rowptr, cursor);
    scatter_kernel<<<NE / 256, 256, 0, stream>>>(ei, cursor, csr_src, csr_e);

    // ======================= GAT path (F=64, softmax on trg) ================
    hipMemsetAsync(ssrc, 0, (size_t)NN * 12 * sizeof(float), stream);  // ssrc+strg+den
    mfma_gemm<128, 160,  64, 128,  64, true , false,  64><<<dim3(256, 1), 256, 0, stream>>>(
        cb, wt_gp, bgp, nullptr, x_pb, nullptr, nullptr, nullptr, nullptr);
    mfma_gemm< 64,  64, 256, 128, 128, true , true ,  64><<<dim3(256, 2), 256, 0, stream>>>(
        x_pb, wt_g, nullptr, nullptr, proj_b, ags, agt, ssrc, strg);
    edge_kernel<false><<<NE / 256, 256, 0, stream>>>(ei, ssrc, strg, ex, den);
    aggregate_csr<64, 4, false><<<NN / 4, dim3(64, 4), 0, stream>>>(
        rowptr, csr_src, csr_e, proj_b, ex, nullptr, x_pb, bg, aggb);
    mfma_gemm< 64,  64, 128, 128, 128, false, false,  64><<<dim3(256, 1), 256, 0, stream>>>(
        aggb, wt_gr, bgr, out_gat, nullptr, nullptr, nullptr, nullptr, nullptr);

    // ====================== Cross path (F=96, softmax on src) ===============
    hipMemsetAsync(ssrc, 0, (size_t)NN * 12 * sizeof(float), stream);  // ssrc+strg+den
    mfma_gemm<160, 160,  96,  64,  96, true , false,  96><<<dim3(512, 1), 256, 0, stream>>>(
        cb, wt_cp, bcp, nullptr, x_pb, nullptr, nullptr, nullptr, nullptr);
    mfma_gemm< 96,  96, 384, 128, 128, true , true ,  96><<<dim3(256, 3), 256, 0, stream>>>(
        x_pb, wt_c, nullptr, nullptr, proj_b, acs, act, ssrc, strg);
    edge_kernel<true><<<NE / 256, 256, 0, stream>>>(ei, ssrc, strg, ex, den);
    aggregate_csr<96, 2, true><<<NN / 2, dim3(96, 2), 0, stream>>>(
        rowptr, csr_src, csr_e, proj_b, ex, den, x_pb, bc, aggb);
    mfma_gemm< 96,  96, 160, 128,  80, false, false,  96><<<dim3(256, 2), 256, 0, stream>>>(
        aggb, wt_cr, bcr, out_cross, nullptr, nullptr, nullptr, nullptr, nullptr);
}

// Round 7
// 229.449 us; speedup vs baseline: 1.4877x; 1.4847x over previous
//
#include <hip/hip_runtime.h>
#include <hip/hip_bf16.h>

#define NN 32768      // nodes
#define NE 131072     // edges
#define HH 4          // heads

constexpr float kLrelu = 0.2f;

using bf16x8 = __attribute__((ext_vector_type(8))) __bf16;
using f32x4  = __attribute__((ext_vector_type(4))) float;

__device__ inline short f2b(float f) {
    __hip_bfloat16 h = __float2bfloat16(f);          // RTNE
    return __builtin_bit_cast(short, h);
}
__device__ inline float b2f(short s) {
    __hip_bfloat16 h = __builtin_bit_cast(__hip_bfloat16, s);
    return __bfloat162float(h);
}
__device__ inline float blo(int u) {                 // bf16 in bits[15:0]
    return __builtin_bit_cast(float, (int)(u << 16));
}
__device__ inline float bhi(int u) {                 // bf16 in bits[31:16]
    return __builtin_bit_cast(float, (int)(u & 0xffff0000));
}

// ---------------------------------------------------------------------------
// LDS-staged bf16 MFMA GEMM: C[M,OUTN] = A[M,K](bf16, row stride LDA) @ Wt^T.
// Wt is [OUTN,K] bf16. Tile BM x BN, 4 waves (WM x WN). +8-short row pad.
// C/D frag layout (m89-verified): row=(lane>>4)*4+j, col=lane&15.
// Epilogue: acc -> per-wave LDS slice (reusing As/Bs) -> coalesced 16B/lane
// global stores. No atomics anywhere.
// ---------------------------------------------------------------------------
template<int K, int LDA, int OUTN, int BM, int BN, bool BF16OUT>
__global__ __launch_bounds__(256) void mfma_gemm(
    const short* __restrict__ A, const short* __restrict__ Wt,
    const float* __restrict__ bias,
    float* __restrict__ Cf, short* __restrict__ Cb)
{
    constexpr int KP    = K + 8;           // padded LDS row (shorts)
    constexpr int WM    = BM / 32;         // waves along rows
    constexpr int WN    = 4 / WM;          // waves along cols
    constexpr int WBN   = BN / WN;         // cols per wave
    constexpr int CF    = WBN / 16;        // col frags per wave
    constexpr int CPR   = K / 8;           // 16B chunks per K-row
    constexpr int TOT   = (BM + BN) * KP;  // total LDS shorts
    constexpr int SLICE = TOT / 4;         // per-wave epilogue slice (shorts)

    __shared__ short lds[TOT];
    short* As = lds;
    short* Bs = lds + BM * KP;

    const int tid  = threadIdx.x;
    const int wave = tid >> 6;
    const int lane = tid & 63;
    const int lr   = lane & 15;
    const int kb   = lane >> 4;            // 0..3
    const int wm   = wave % WM;
    const int wn   = wave / WM;
    const int row0 = blockIdx.x * BM;
    const int col0 = blockIdx.y * BN;

    // ---- stage A tile (coalesced 16B chunks) ----
    #pragma unroll
    for (int g = tid; g < BM * CPR; g += 256) {
        int r = g / CPR, c = g - r * CPR;
        bf16x8 v = *(const bf16x8*)(A + (size_t)(row0 + r) * LDA + c * 8);
        *(bf16x8*)(As + r * KP + c * 8) = v;
    }
    // ---- stage B tile ----
    #pragma unroll
    for (int g = tid; g < BN * CPR; g += 256) {
        int r = g / CPR, c = g - r * CPR;
        bf16x8 v = *(const bf16x8*)(Wt + (size_t)(col0 + r) * K + c * 8);
        *(bf16x8*)(Bs + r * KP + c * 8) = v;
    }
    __syncthreads();

    // ---- MFMA K-loop from LDS ----
    f32x4 acc[2][CF] = {};
    #pragma unroll
    for (int k0 = 0; k0 < K; k0 += 32) {
        bf16x8 af0 = *(const bf16x8*)(As + (wm * 32 + lr     ) * KP + k0 + kb * 8);
        bf16x8 af1 = *(const bf16x8*)(As + (wm * 32 + lr + 16) * KP + k0 + kb * 8);
        #pragma unroll
        for (int cf = 0; cf < CF; ++cf) {
            bf16x8 bv = *(const bf16x8*)(Bs + (wn * WBN + cf * 16 + lr) * KP + k0 + kb * 8);
            acc[0][cf] = __builtin_amdgcn_mfma_f32_16x16x32_bf16(af0, bv, acc[0][cf], 0, 0, 0);
            acc[1][cf] = __builtin_amdgcn_mfma_f32_16x16x32_bf16(af1, bv, acc[1][cf], 0, 0, 0);
        }
    }

    // ---- coalesced C epilogue via per-wave LDS slice (reuses As/Bs) ----
    #pragma unroll
    for (int mf = 0; mf < 2; ++mf) {
        __syncthreads();   // previous LDS readers done
        if constexpr (BF16OUT) {
            constexpr int LEP = WBN + 8;               // shorts per slice row
            short* ep = lds + wave * SLICE;
            #pragma unroll
            for (int cf = 0; cf < CF; ++cf) {
                const int c  = cf * 16 + lr;
                const float bv = bias ? bias[col0 + wn * WBN + c] : 0.0f;
                #pragma unroll
                for (int j = 0; j < 4; ++j)
                    ep[(kb * 4 + j) * LEP + c] = f2b(acc[mf][cf][j] + bv);
            }
            __syncthreads();
            constexpr int CROW = WBN / 8;              // 16B chunks per row
            for (int g = lane; g < 16 * CROW; g += 64) {
                int r = g / CROW, cc = g - r * CROW;
                bf16x8 v = *(const bf16x8*)(ep + r * LEP + cc * 8);
                *(bf16x8*)(Cb + (size_t)(row0 + wm * 32 + mf * 16 + r) * OUTN
                              + col0 + wn * WBN + cc * 8) = v;
            }
        } else {
            constexpr int LEPF = WBN + 4;              // floats per slice row
            float* epf = (float*)(lds + wave * SLICE);
            #pragma unroll
            for (int cf = 0; cf < CF; ++cf) {
                const int c  = cf * 16 + lr;
                const float bv = bias ? bias[col0 + wn * WBN + c] : 0.0f;
                #pragma unroll
                for (int j = 0; j < 4; ++j)
                    epf[(kb * 4 + j) * LEPF + c] = acc[mf][cf][j] + bv;
            }
            __syncthreads();
            constexpr int CROWF = WBN / 4;             // 16B chunks per row
            for (int g = lane; g < 16 * CROWF; g += 64) {
                int r = g / CROWF, cc = g - r * CROWF;
                float4 v = *(const float4*)(epf + r * LEPF + cc * 4);
                *(float4*)(Cf + (size_t)(row0 + wm * 32 + mf * 16 + r) * OUTN
                              + col0 + wn * WBN + cc * 4) = v;
            }
        }
    }
}

// ---------------------------------------------------------------------------
// Node scores from stored proj (round-2-proven formulation, bf16 source):
// s_src[n,h] = sum_f proj[n,h,f]*a_src[h,f]; same for trg. Thread = (n,h).
// int4 loads + bit-unpack; f32 accumulate. No atomics.
// ---------------------------------------------------------------------------
template<int F>
__global__ __launch_bounds__(256) void scores_proj(
    const short* __restrict__ proj_b,
    const float* __restrict__ a_src, const float* __restrict__ a_trg,
    float* __restrict__ ssrc, float* __restrict__ strg)
{
    int t = blockIdx.x * 256 + threadIdx.x;
    if (t >= NN * HH) return;
    int n = t >> 2, h = t & 3;
    const int4* p = (const int4*)(proj_b + (size_t)n * (4 * F) + h * F);
    const float* as = a_src + h * F;
    const float* at = a_trg + h * F;
    float ss = 0.f, st = 0.f;
    #pragma unroll
    for (int c = 0; c < F / 8; ++c) {
        int4 v = p[c];
        int u[4] = { v.x, v.y, v.z, v.w };
        #pragma unroll
        for (int q = 0; q < 4; ++q) {
            float x0 = blo(u[q]), x1 = bhi(u[q]);
            ss += x0 * as[c * 8 + 2 * q] + x1 * as[c * 8 + 2 * q + 1];
            st += x0 * at[c * 8 + 2 * q] + x1 * at[c * 8 + 2 * q + 1];
        }
    }
    ssrc[t] = ss;
    strg[t] = st;
}

// ---------------------------------------------------------------------------
// All 6 weight transposes (fp32 -> bf16, [K,N] -> [N,K]) in one launch.
// ---------------------------------------------------------------------------
__global__ __launch_bounds__(256) void wt_all_kernel(
    const float* W0, const float* W1, const float* W2,
    const float* W3, const float* W4, const float* W5,
    short* T0, short* T1, short* T2, short* T3, short* T4, short* T5)
{
    int K, N; const float* W; short* T;
    switch (blockIdx.y) {
        case 0: K = 128; N =  64; W = W0; T = T0; break;
        case 1: K =  64; N = 256; W = W1; T = T1; break;
        case 2: K =  64; N = 128; W = W2; T = T2; break;
        case 3: K = 160; N =  96; W = W3; T = T3; break;
        case 4: K =  96; N = 384; W = W4; T = T4; break;
        default:K =  96; N = 160; W = W5; T = T5; break;
    }
    int t = blockIdx.x * 256 + threadIdx.x;
    if (t >= K * N) return;
    int n = t / K, k = t - n * K;
    T[t] = f2b(W[(size_t)k * N + n]);
}

// ---------------------------------------------------------------------------
// Build bf16 concat [N,160] = [rna | prot]
// ---------------------------------------------------------------------------
__global__ __launch_bounds__(256) void concat_kernel(
    const float* __restrict__ rna, const float* __restrict__ prot,
    short* __restrict__ cb)
{
    int t = blockIdx.x * 256 + threadIdx.x;
    if (t >= NN * 40) return;
    int n = t / 40, j = (t - n * 40) * 4;
    float4 v = (j < 128) ? *(const float4*)(rna  + (size_t)n * 128 + j)
                         : *(const float4*)(prot + (size_t)n * 32 + (j - 128));
    short4 o = { f2b(v.x), f2b(v.y), f2b(v.z), f2b(v.w) };
    *(short4*)(cb + (size_t)n * 160 + j) = o;
}

// ---------------------------------------------------------------------------
// Dual CSR build: grouped-by-trg (shared aggregate) AND grouped-by-src
// (cross denominators).
// ---------------------------------------------------------------------------
__global__ __launch_bounds__(256) void hist_dual(const int* __restrict__ ei,
                                                 int* __restrict__ deg_t,
                                                 int* __restrict__ deg_s)
{
    int e = blockIdx.x * 256 + threadIdx.x;
    if (e >= NE) return;
    atomicAdd(&deg_s[ei[e]], 1);
    atomicAdd(&deg_t[ei[NE + e]], 1);
}

__global__ __launch_bounds__(1024) void scan_dual(
    const int* __restrict__ deg_t, int* __restrict__ rowptr_t, int* __restrict__ cursor_t,
    const int* __restrict__ deg_s, int* __restrict__ rowptr_s, int* __restrict__ cursor_s)
{
    const int* deg    = blockIdx.x ? deg_s    : deg_t;
    int*       rowptr = blockIdx.x ? rowptr_s : rowptr_t;
    int*       cursor = blockIdx.x ? cursor_s : cursor_t;
    __shared__ int sums[1024];
    const int t = threadIdx.x;
    const int base = t * 32;
    int local[32];
    int s = 0;
    #pragma unroll
    for (int i = 0; i < 32; ++i) { local[i] = s; s += deg[base + i]; }
    sums[t] = s;
    __syncthreads();
    for (int off = 1; off < 1024; off <<= 1) {
        int v = (t >= off) ? sums[t - off] : 0;
        __syncthreads();
        sums[t] += v;
        __syncthreads();
    }
    const int prev = (t == 0) ? 0 : sums[t - 1];
    #pragma unroll
    for (int i = 0; i < 32; ++i) {
        rowptr[base + i] = prev + local[i];
        cursor[base + i] = prev + local[i];
    }
    if (t == 1023) rowptr[NN] = prev + s;
}

__global__ __launch_bounds__(256) void scatter_dual(
    const int* __restrict__ ei,
    int* __restrict__ cursor_t, int* __restrict__ csr_srcT, int* __restrict__ csr_eT,
    int* __restrict__ cursor_s, int* __restrict__ csr_eS)
{
    int e = blockIdx.x * 256 + threadIdx.x;
    if (e >= NE) return;
    int s = ei[e], t = ei[NE + e];
    int st = atomicAdd(&cursor_t[t], 1);
    csr_srcT[st] = s;
    csr_eT[st]   = e;
    int ss = atomicAdd(&cursor_s[s], 1);
    csr_eS[ss]   = e;
}

// ---------------------------------------------------------------------------
// Per-edge exp(lrelu(score)). No atomics.
// ---------------------------------------------------------------------------
__global__ __launch_bounds__(256) void edge_kernel(
    const int* __restrict__ ei,
    const float* __restrict__ s_src, const float* __restrict__ s_trg,
    float* __restrict__ ex)
{
    int e = blockIdx.x * 256 + threadIdx.x;
    if (e >= NE) return;
    int s = ei[e], t = ei[NE + e];
    const float4 ss = *(const float4*)(s_src + 4 * (size_t)s);
    const float4 st = *(const float4*)(s_trg + 4 * (size_t)t);
    float sc[4] = { ss.x + st.x, ss.y + st.y, ss.z + st.z, ss.w + st.w };
    float ev[4];
    #pragma unroll
    for (int h = 0; h < 4; ++h) {
        float x  = sc[h];
        float lr = x > 0.f ? x : kLrelu * x;
        ev[h] = expf(lr);
    }
    *(float4*)(ex + 4 * (size_t)e) = make_float4(ev[0], ev[1], ev[2], ev[3]);
}

// ---------------------------------------------------------------------------
// Cross denominators via src-CSR (atomic-free): den[n] = sum_{e: src=n} ex[e].
// ---------------------------------------------------------------------------
__global__ __launch_bounds__(256) void den_src_kernel(
    const int* __restrict__ rowptr_s, const int* __restrict__ csr_eS,
    const float* __restrict__ ex, float* __restrict__ den)
{
    int n = blockIdx.x * 256 + threadIdx.x;
    if (n >= NN) return;
    const int beg = rowptr_s[n], end = rowptr_s[n + 1];
    float d0 = 0.f, d1 = 0.f, d2 = 0.f, d3 = 0.f;
    for (int sl = beg; sl < end; ++sl) {
        const float4 ev = *(const float4*)(ex + 4 * (size_t)csr_eS[sl]);
        d0 += ev.x; d1 += ev.y; d2 += ev.z; d3 += ev.w;
    }
    *(float4*)(den + 4 * (size_t)n) = make_float4(d0, d1, d2, d3);
}

// ---------------------------------------------------------------------------
// CSR aggregation, atomic-free, fused mean+skip+bias -> bf16.
// GROUP_SRC=false (GAT): softmax group == trg -> denominator in-kernel.
// GROUP_SRC=true (cross): denominators gathered from den[src].
// ---------------------------------------------------------------------------
template<int F, int NPB, bool GROUP_SRC>
__global__ __launch_bounds__(F * NPB) void aggregate_csr(
    const int* __restrict__ rowptr, const int* __restrict__ csr_src,
    const int* __restrict__ csr_e,
    const short* __restrict__ proj_b, const float* __restrict__ ex,
    const float* __restrict__ den,
    const short* __restrict__ x_pb, const float* __restrict__ bias,
    short* __restrict__ aggb)
{
    const int f    = threadIdx.x;
    const int node = blockIdx.x * NPB + threadIdx.y;
    const int beg  = rowptr[node], end = rowptr[node + 1];
    float acc = 0.f;

    if constexpr (!GROUP_SRC) {
        float d0 = 0.f, d1 = 0.f, d2 = 0.f, d3 = 0.f;
        for (int sl = beg; sl < end; ++sl) {
            const float4 ev = *(const float4*)(ex + 4 * (size_t)csr_e[sl]);
            d0 += ev.x; d1 += ev.y; d2 += ev.z; d3 += ev.w;
        }
        const float r0 = 1.f / (d0 + 1e-16f), r1 = 1.f / (d1 + 1e-16f);
        const float r2 = 1.f / (d2 + 1e-16f), r3 = 1.f / (d3 + 1e-16f);
        for (int sl = beg; sl < end; ++sl) {
            const int s = csr_src[sl];
            const float4 ev = *(const float4*)(ex + 4 * (size_t)csr_e[sl]);
            const short* p = proj_b + (size_t)s * (4 * F) + f;
            acc += b2f(p[0])     * (ev.x * r0) + b2f(p[F])     * (ev.y * r1)
                 + b2f(p[2 * F]) * (ev.z * r2) + b2f(p[3 * F]) * (ev.w * r3);
        }
    } else {
        for (int sl = beg; sl < end; ++sl) {
            const int s = csr_src[sl];
            const float4 ev = *(const float4*)(ex  + 4 * (size_t)csr_e[sl]);
            const float4 dv = *(const float4*)(den + 4 * (size_t)s);
            const short* p = proj_b + (size_t)s * (4 * F) + f;
            acc += b2f(p[0])     * (ev.x / (dv.x + 1e-16f))
                 + b2f(p[F])     * (ev.y / (dv.y + 1e-16f))
                 + b2f(p[2 * F]) * (ev.z / (dv.z + 1e-16f))
                 + b2f(p[3 * F]) * (ev.w / (dv.w + 1e-16f));
        }
    }
    const int o = node * F + f;
    aggb[o] = f2b(acc * 0.25f + b2f(x_pb[o]) + bias[f]);
}

// ---------------------------------------------------------------------------
extern "C" void kernel_launch(void* const* d_in, const int* in_sizes, int n_in,
                              void* d_out, int out_size, void* d_ws, size_t ws_size,
                              hipStream_t stream)
{
    const float* rna   = (const float*)d_in[0];    // [N,128]
    const float* prot  = (const float*)d_in[1];    // [N,32]
    const int*   ei    = (const int*)  d_in[2];    // [2,E]
    const float* Wgp   = (const float*)d_in[3];    // [128,64]
    const float* bgp   = (const float*)d_in[4];
    const float* Wgr   = (const float*)d_in[5];    // [64,128]
    const float* bgr   = (const float*)d_in[6];
    const float* Wg    = (const float*)d_in[7];    // [64,256]
    const float* ags   = (const float*)d_in[8];    // [4,64]
    const float* agt   = (const float*)d_in[9];
    const float* bg    = (const float*)d_in[10];   // [64]
    const float* Wcp   = (const float*)d_in[11];   // [160,96]
    const float* bcp   = (const float*)d_in[12];
    const float* Wcr   = (const float*)d_in[13];   // [96,160]
    const float* bcr   = (const float*)d_in[14];
    const float* Wc    = (const float*)d_in[15];   // [96,384]
    const float* acs   = (const float*)d_in[16];   // [4,96]
    const float* act   = (const float*)d_in[17];
    const float* bc    = (const float*)d_in[18];   // [96]

    float* out_gat   = (float*)d_out;              // [N,128]
    float* out_cross = out_gat + (size_t)NN * 128; // [N,160]

    // ---- workspace layout ----
    float* ex     = (float*)d_ws;                  // E*4 f32
    float* ssrc   = ex   + (size_t)NE * 4;         // N*4 f32
    float* strg   = ssrc + (size_t)NN * 4;         // N*4 f32
    float* den    = strg + (size_t)NN * 4;         // N*4 f32
    short* proj_b = (short*)(den + (size_t)NN * 4);// N*384 bf16
    short* cb     = proj_b + (size_t)NN * 384;     // N*160 bf16
    short* x_pb   = cb    + (size_t)NN * 160;      // N*96 bf16
    short* aggb   = x_pb  + (size_t)NN * 96;       // N*96 bf16
    short* wt_gp  = aggb  + (size_t)NN * 96;       // [64,128]
    short* wt_g   = wt_gp + 128 * 64;              // [256,64]
    short* wt_gr  = wt_g  + 64 * 256;              // [128,64]
    short* wt_cp  = wt_gr + 64 * 128;              // [96,160]
    short* wt_c   = wt_cp + 160 * 96;              // [384,96]
    short* wt_cr  = wt_c  + 96 * 384;              // [160,96]
    int*   deg_t  = (int*)(wt_cr + 96 * 160);      // N
    int*   deg_s  = deg_t  + NN;                   // N  (adjacent: one memset)
    int*   cursor_t = deg_s  + NN;                 // N
    int*   cursor_s = cursor_t + NN;               // N
    int*   rowptr_t = cursor_s + NN;               // N+1
    int*   rowptr_s = rowptr_t + NN + 1;           // N+1
    int*   csr_srcT = rowptr_s + NN + 1;           // E
    int*   csr_eT   = csr_srcT + NE;               // E
    int*   csr_eS   = csr_eT   + NE;               // E

    // ---- one-time converts + dual CSR build ----
    concat_kernel<<<(NN * 40 + 255) / 256, 256, 0, stream>>>(rna, prot, cb);
    wt_all_kernel<<<dim3(144, 6), 256, 0, stream>>>(Wgp, Wg, Wgr, Wcp, Wc, Wcr,
                                                    wt_gp, wt_g, wt_gr, wt_cp, wt_c, wt_cr);
    hipMemsetAsync(deg_t, 0, (size_t)2 * NN * sizeof(int), stream);
    hist_dual<<<NE / 256, 256, 0, stream>>>(ei, deg_t, deg_s);
    scan_dual<<<2, 1024, 0, stream>>>(deg_t, rowptr_t, cursor_t, deg_s, rowptr_s, cursor_s);
    scatter_dual<<<NE / 256, 256, 0, stream>>>(ei, cursor_t, csr_srcT, csr_eT, cursor_s, csr_eS);

    // ======================= GAT path (F=64, softmax on trg) ================
    mfma_gemm<128, 160,  64, 128,  64, true ><<<dim3(256, 1), 256, 0, stream>>>(cb,   wt_gp, bgp, nullptr, x_pb);
    mfma_gemm< 64,  64, 256, 128, 128, true ><<<dim3(256, 2), 256, 0, stream>>>(x_pb, wt_g,  nullptr, nullptr, proj_b);
    scores_proj<64><<<(NN * HH) / 256, 256, 0, stream>>>(proj_b, ags, agt, ssrc, strg);
    edge_kernel<<<NE / 256, 256, 0, stream>>>(ei, ssrc, strg, ex);
    aggregate_csr<64, 4, false><<<NN / 4, dim3(64, 4), 0, stream>>>(
        rowptr_t, csr_srcT, csr_eT, proj_b, ex, nullptr, x_pb, bg, aggb);
    mfma_gemm< 64,  64, 128, 128, 128, false><<<dim3(256, 1), 256, 0, stream>>>(aggb, wt_gr, bgr, out_gat, nullptr);

    // ====================== Cross path (F=96, softmax on src) ===============
    mfma_gemm<160, 160,  96,  64,  96, true ><<<dim3(512, 1), 256, 0, stream>>>(cb,   wt_cp, bcp, nullptr, x_pb);
    mfma_gemm< 96,  96, 384, 128, 128, true ><<<dim3(256, 3), 256, 0, stream>>>(x_pb, wt_c,  nullptr, nullptr, proj_b);
    scores_proj<96><<<(NN * HH) / 256, 256, 0, stream>>>(proj_b, acs, act, ssrc, strg);
    edge_kernel<<<NE / 256, 256, 0, stream>>>(ei, ssrc, strg, ex);
    den_src_kernel<<<NN / 256, 256, 0, stream>>>(rowptr_s, csr_eS, ex, den);
    aggregate_csr<96, 2, true><<<NN / 2, dim3(96, 2), 0, stream>>>(
        rowptr_t, csr_srcT, csr_eT, proj_b, ex, den, x_pb, bc, aggb);
    mfma_gemm< 96,  96, 160, 128,  80, false><<<dim3(256, 2), 256, 0, stream>>>(aggb, wt_cr, bcr, out_cross, nullptr);
}

// Round 8
// 206.645 us; speedup vs baseline: 1.6518x; 1.1104x over previous
//
#include <hip/hip_runtime.h>
#include <hip/hip_bf16.h>

#define NN 32768      // nodes
#define NE 131072     // edges
#define HH 4          // heads

constexpr float kLrelu = 0.2f;

using bf16x8 = __attribute__((ext_vector_type(8))) __bf16;
using f32x4  = __attribute__((ext_vector_type(4))) float;

__device__ inline short f2b(float f) {
    __hip_bfloat16 h = __float2bfloat16(f);          // RTNE
    return __builtin_bit_cast(short, h);
}
__device__ inline float b2f(short s) {
    __hip_bfloat16 h = __builtin_bit_cast(__hip_bfloat16, s);
    return __bfloat162float(h);
}
__device__ inline float blo(int u) {                 // bf16 in bits[15:0]
    return __builtin_bit_cast(float, (int)(u << 16));
}
__device__ inline float bhi(int u) {                 // bf16 in bits[31:16]
    return __builtin_bit_cast(float, (int)(u & 0xffff0000));
}
__device__ inline float lrexp(float x) {             // exp(leaky_relu(x))
    return __expf(x > 0.f ? x : kLrelu * x);
}

// ---------------------------------------------------------------------------
// LDS-staged bf16 MFMA GEMM (unchanged from round 7, proven).
// ---------------------------------------------------------------------------
template<int K, int LDA, int OUTN, int BM, int BN, bool BF16OUT>
__global__ __launch_bounds__(256) void mfma_gemm(
    const short* __restrict__ A, const short* __restrict__ Wt,
    const float* __restrict__ bias,
    float* __restrict__ Cf, short* __restrict__ Cb)
{
    constexpr int KP    = K + 8;           // padded LDS row (shorts)
    constexpr int WM    = BM / 32;         // waves along rows
    constexpr int WN    = 4 / WM;          // waves along cols
    constexpr int WBN   = BN / WN;         // cols per wave
    constexpr int CF    = WBN / 16;        // col frags per wave
    constexpr int CPR   = K / 8;           // 16B chunks per K-row
    constexpr int TOT   = (BM + BN) * KP;  // total LDS shorts
    constexpr int SLICE = TOT / 4;         // per-wave epilogue slice (shorts)

    __shared__ short lds[TOT];
    short* As = lds;
    short* Bs = lds + BM * KP;

    const int tid  = threadIdx.x;
    const int wave = tid >> 6;
    const int lane = tid & 63;
    const int lr   = lane & 15;
    const int kb   = lane >> 4;            // 0..3
    const int wm   = wave % WM;
    const int wn   = wave / WM;
    const int row0 = blockIdx.x * BM;
    const int col0 = blockIdx.y * BN;

    #pragma unroll
    for (int g = tid; g < BM * CPR; g += 256) {
        int r = g / CPR, c = g - r * CPR;
        bf16x8 v = *(const bf16x8*)(A + (size_t)(row0 + r) * LDA + c * 8);
        *(bf16x8*)(As + r * KP + c * 8) = v;
    }
    #pragma unroll
    for (int g = tid; g < BN * CPR; g += 256) {
        int r = g / CPR, c = g - r * CPR;
        bf16x8 v = *(const bf16x8*)(Wt + (size_t)(col0 + r) * K + c * 8);
        *(bf16x8*)(Bs + r * KP + c * 8) = v;
    }
    __syncthreads();

    f32x4 acc[2][CF] = {};
    #pragma unroll
    for (int k0 = 0; k0 < K; k0 += 32) {
        bf16x8 af0 = *(const bf16x8*)(As + (wm * 32 + lr     ) * KP + k0 + kb * 8);
        bf16x8 af1 = *(const bf16x8*)(As + (wm * 32 + lr + 16) * KP + k0 + kb * 8);
        #pragma unroll
        for (int cf = 0; cf < CF; ++cf) {
            bf16x8 bv = *(const bf16x8*)(Bs + (wn * WBN + cf * 16 + lr) * KP + k0 + kb * 8);
            acc[0][cf] = __builtin_amdgcn_mfma_f32_16x16x32_bf16(af0, bv, acc[0][cf], 0, 0, 0);
            acc[1][cf] = __builtin_amdgcn_mfma_f32_16x16x32_bf16(af1, bv, acc[1][cf], 0, 0, 0);
        }
    }

    #pragma unroll
    for (int mf = 0; mf < 2; ++mf) {
        __syncthreads();
        if constexpr (BF16OUT) {
            constexpr int LEP = WBN + 8;
            short* ep = lds + wave * SLICE;
            #pragma unroll
            for (int cf = 0; cf < CF; ++cf) {
                const int c  = cf * 16 + lr;
                const float bv = bias ? bias[col0 + wn * WBN + c] : 0.0f;
                #pragma unroll
                for (int j = 0; j < 4; ++j)
                    ep[(kb * 4 + j) * LEP + c] = f2b(acc[mf][cf][j] + bv);
            }
            __syncthreads();
            constexpr int CROW = WBN / 8;
            for (int g = lane; g < 16 * CROW; g += 64) {
                int r = g / CROW, cc = g - r * CROW;
                bf16x8 v = *(const bf16x8*)(ep + r * LEP + cc * 8);
                *(bf16x8*)(Cb + (size_t)(row0 + wm * 32 + mf * 16 + r) * OUTN
                              + col0 + wn * WBN + cc * 8) = v;
            }
        } else {
            constexpr int LEPF = WBN + 4;
            float* epf = (float*)(lds + wave * SLICE);
            #pragma unroll
            for (int cf = 0; cf < CF; ++cf) {
                const int c  = cf * 16 + lr;
                const float bv = bias ? bias[col0 + wn * WBN + c] : 0.0f;
                #pragma unroll
                for (int j = 0; j < 4; ++j)
                    epf[(kb * 4 + j) * LEPF + c] = acc[mf][cf][j] + bv;
            }
            __syncthreads();
            constexpr int CROWF = WBN / 4;
            for (int g = lane; g < 16 * CROWF; g += 64) {
                int r = g / CROWF, cc = g - r * CROWF;
                float4 v = *(const float4*)(epf + r * LEPF + cc * 4);
                *(float4*)(Cf + (size_t)(row0 + wm * 32 + mf * 16 + r) * OUTN
                              + col0 + wn * WBN + cc * 4) = v;
            }
        }
    }
}

// ---------------------------------------------------------------------------
// Node scores from stored proj (round-7-proven): s[n,h] = sum_f proj*a.
// ---------------------------------------------------------------------------
template<int F>
__global__ __launch_bounds__(256) void scores_proj(
    const short* __restrict__ proj_b,
    const float* __restrict__ a_src, const float* __restrict__ a_trg,
    float* __restrict__ ssrc, float* __restrict__ strg)
{
    int t = blockIdx.x * 256 + threadIdx.x;
    if (t >= NN * HH) return;
    int n = t >> 2, h = t & 3;
    const int4* p = (const int4*)(proj_b + (size_t)n * (4 * F) + h * F);
    const float* as = a_src + h * F;
    const float* at = a_trg + h * F;
    float ss = 0.f, st = 0.f;
    #pragma unroll
    for (int c = 0; c < F / 8; ++c) {
        int4 v = p[c];
        int u[4] = { v.x, v.y, v.z, v.w };
        #pragma unroll
        for (int q = 0; q < 4; ++q) {
            float x0 = blo(u[q]), x1 = bhi(u[q]);
            ss += x0 * as[c * 8 + 2 * q] + x1 * as[c * 8 + 2 * q + 1];
            st += x0 * at[c * 8 + 2 * q] + x1 * at[c * 8 + 2 * q + 1];
        }
    }
    ssrc[t] = ss;
    strg[t] = st;
}

// ---------------------------------------------------------------------------
// All 6 weight transposes (fp32 -> bf16, [K,N] -> [N,K]) in one launch.
// ---------------------------------------------------------------------------
__global__ __launch_bounds__(256) void wt_all_kernel(
    const float* W0, const float* W1, const float* W2,
    const float* W3, const float* W4, const float* W5,
    short* T0, short* T1, short* T2, short* T3, short* T4, short* T5)
{
    int K, N; const float* W; short* T;
    switch (blockIdx.y) {
        case 0: K = 128; N =  64; W = W0; T = T0; break;
        case 1: K =  64; N = 256; W = W1; T = T1; break;
        case 2: K =  64; N = 128; W = W2; T = T2; break;
        case 3: K = 160; N =  96; W = W3; T = T3; break;
        case 4: K =  96; N = 384; W = W4; T = T4; break;
        default:K =  96; N = 160; W = W5; T = T5; break;
    }
    int t = blockIdx.x * 256 + threadIdx.x;
    if (t >= K * N) return;
    int n = t / K, k = t - n * K;
    T[t] = f2b(W[(size_t)k * N + n]);
}

// ---------------------------------------------------------------------------
// Build bf16 concat [N,160] = [rna | prot]
// ---------------------------------------------------------------------------
__global__ __launch_bounds__(256) void concat_kernel(
    const float* __restrict__ rna, const float* __restrict__ prot,
    short* __restrict__ cb)
{
    int t = blockIdx.x * 256 + threadIdx.x;
    if (t >= NN * 40) return;
    int n = t / 40, j = (t - n * 40) * 4;
    float4 v = (j < 128) ? *(const float4*)(rna  + (size_t)n * 128 + j)
                         : *(const float4*)(prot + (size_t)n * 32 + (j - 128));
    short4 o = { f2b(v.x), f2b(v.y), f2b(v.z), f2b(v.w) };
    *(short4*)(cb + (size_t)n * 160 + j) = o;
}

// ---------------------------------------------------------------------------
// Fast zeroing (replaces 42us rocclr fillBuffer): int4 stores, full grid.
// ---------------------------------------------------------------------------
__global__ __launch_bounds__(256) void zero_kernel(int4* __restrict__ p)
{
    p[blockIdx.x * 256 + threadIdx.x] = make_int4(0, 0, 0, 0);
}

// ---------------------------------------------------------------------------
// Dual CSR build. trg-CSR stores src per slot; src-CSR stores trg per slot
// plus the src-slot -> trg-slot map (for writing attn in trg order).
// ---------------------------------------------------------------------------
__global__ __launch_bounds__(256) void hist_dual(const int* __restrict__ ei,
                                                 int* __restrict__ deg_t,
                                                 int* __restrict__ deg_s)
{
    int e = blockIdx.x * 256 + threadIdx.x;
    if (e >= NE) return;
    atomicAdd(&deg_s[ei[e]], 1);
    atomicAdd(&deg_t[ei[NE + e]], 1);
}

__global__ __launch_bounds__(1024) void scan_dual(
    const int* __restrict__ deg_t, int* __restrict__ rowptr_t, int* __restrict__ cursor_t,
    const int* __restrict__ deg_s, int* __restrict__ rowptr_s, int* __restrict__ cursor_s)
{
    const int* deg    = blockIdx.x ? deg_s    : deg_t;
    int*       rowptr = blockIdx.x ? rowptr_s : rowptr_t;
    int*       cursor = blockIdx.x ? cursor_s : cursor_t;
    __shared__ int sums[1024];
    const int t = threadIdx.x;
    const int base = t * 32;
    int local[32];
    int s = 0;
    #pragma unroll
    for (int i = 0; i < 32; ++i) { local[i] = s; s += deg[base + i]; }
    sums[t] = s;
    __syncthreads();
    for (int off = 1; off < 1024; off <<= 1) {
        int v = (t >= off) ? sums[t - off] : 0;
        __syncthreads();
        sums[t] += v;
        __syncthreads();
    }
    const int prev = (t == 0) ? 0 : sums[t - 1];
    #pragma unroll
    for (int i = 0; i < 32; ++i) {
        rowptr[base + i] = prev + local[i];
        cursor[base + i] = prev + local[i];
    }
    if (t == 1023) rowptr[NN] = prev + s;
}

__global__ __launch_bounds__(256) void scatter_dual(
    const int* __restrict__ ei,
    int* __restrict__ cursor_t, int* __restrict__ csr_srcT,
    int* __restrict__ cursor_s, int* __restrict__ csr_trgS,
    int* __restrict__ map_s2t)
{
    int e = blockIdx.x * 256 + threadIdx.x;
    if (e >= NE) return;
    int s = ei[e], t = ei[NE + e];
    int st = atomicAdd(&cursor_t[t], 1);
    csr_srcT[st] = s;
    int ss = atomicAdd(&cursor_s[s], 1);
    csr_trgS[ss] = t;
    map_s2t[ss]  = st;
}

// ---------------------------------------------------------------------------
// GAT den+attn (softmax grouped by trg): node-parallel over trg-CSR.
// Pass 1 sums exp(lrelu(ssrc[src]+strg[n])); pass 2 writes normalized attn
// SEQUENTIALLY into attnT (trg-slot order). Score tables are L2-resident.
// ---------------------------------------------------------------------------
__global__ __launch_bounds__(256) void gat_denattn(
    const int* __restrict__ rowptr_t, const int* __restrict__ csr_srcT,
    const float* __restrict__ ssrc, const float* __restrict__ strg,
    float* __restrict__ attnT)
{
    int n = blockIdx.x * 256 + threadIdx.x;
    if (n >= NN) return;
    const int beg = rowptr_t[n], end = rowptr_t[n + 1];
    const float4 stv = *(const float4*)(strg + 4 * (size_t)n);
    float d0 = 0.f, d1 = 0.f, d2 = 0.f, d3 = 0.f;
    for (int sl = beg; sl < end; ++sl) {
        const int s = csr_srcT[sl];
        const float4 sv = *(const float4*)(ssrc + 4 * (size_t)s);
        d0 += lrexp(sv.x + stv.x); d1 += lrexp(sv.y + stv.y);
        d2 += lrexp(sv.z + stv.z); d3 += lrexp(sv.w + stv.w);
    }
    const float r0 = 1.f / (d0 + 1e-16f), r1 = 1.f / (d1 + 1e-16f);
    const float r2 = 1.f / (d2 + 1e-16f), r3 = 1.f / (d3 + 1e-16f);
    for (int sl = beg; sl < end; ++sl) {
        const int s = csr_srcT[sl];
        const float4 sv = *(const float4*)(ssrc + 4 * (size_t)s);
        *(float4*)(attnT + 4 * (size_t)sl) =
            make_float4(lrexp(sv.x + stv.x) * r0, lrexp(sv.y + stv.y) * r1,
                        lrexp(sv.z + stv.z) * r2, lrexp(sv.w + stv.w) * r3);
    }
}

// ---------------------------------------------------------------------------
// Cross den+attn (softmax grouped by src): node-parallel over src-CSR.
// Pass 2 scatters normalized attn into trg-slot order via map_s2t.
// ---------------------------------------------------------------------------
__global__ __launch_bounds__(256) void cross_denattn(
    const int* __restrict__ rowptr_s, const int* __restrict__ csr_trgS,
    const int* __restrict__ map_s2t,
    const float* __restrict__ ssrc, const float* __restrict__ strg,
    float* __restrict__ attnT)
{
    int n = blockIdx.x * 256 + threadIdx.x;
    if (n >= NN) return;
    const int beg = rowptr_s[n], end = rowptr_s[n + 1];
    const float4 ssv = *(const float4*)(ssrc + 4 * (size_t)n);
    float d0 = 0.f, d1 = 0.f, d2 = 0.f, d3 = 0.f;
    for (int sl = beg; sl < end; ++sl) {
        const int t = csr_trgS[sl];
        const float4 tv = *(const float4*)(strg + 4 * (size_t)t);
        d0 += lrexp(ssv.x + tv.x); d1 += lrexp(ssv.y + tv.y);
        d2 += lrexp(ssv.z + tv.z); d3 += lrexp(ssv.w + tv.w);
    }
    const float r0 = 1.f / (d0 + 1e-16f), r1 = 1.f / (d1 + 1e-16f);
    const float r2 = 1.f / (d2 + 1e-16f), r3 = 1.f / (d3 + 1e-16f);
    for (int sl = beg; sl < end; ++sl) {
        const int t = csr_trgS[sl];
        const float4 tv = *(const float4*)(strg + 4 * (size_t)t);
        *(float4*)(attnT + 4 * (size_t)map_s2t[sl]) =
            make_float4(lrexp(ssv.x + tv.x) * r0, lrexp(ssv.y + tv.y) * r1,
                        lrexp(ssv.z + tv.z) * r2, lrexp(ssv.w + tv.w) * r3);
    }
}

// ---------------------------------------------------------------------------
// Lean SpMM aggregate (identical both paths): acc_f = sum_sl sum_h
// attnT[sl][h] * proj[src][h*F+f]. Sequential attn/src, gathered proj,
// unroll-2 for memory-level parallelism. Fused mean+skip+bias -> bf16.
// ---------------------------------------------------------------------------
template<int F, int NPB>
__global__ __launch_bounds__(F * NPB) void aggregate_lean(
    const int* __restrict__ rowptr_t, const int* __restrict__ csr_srcT,
    const float* __restrict__ attnT, const short* __restrict__ proj_b,
    const short* __restrict__ x_pb, const float* __restrict__ bias,
    short* __restrict__ aggb)
{
    const int f    = threadIdx.x;
    const int node = blockIdx.x * NPB + threadIdx.y;
    const int beg  = rowptr_t[node], end = rowptr_t[node + 1];
    float acc = 0.f;

    int sl = beg;
    for (; sl + 2 <= end; sl += 2) {
        const float4 a0 = *(const float4*)(attnT + 4 * (size_t)sl);
        const float4 a1 = *(const float4*)(attnT + 4 * (size_t)(sl + 1));
        const int s0 = csr_srcT[sl];
        const int s1 = csr_srcT[sl + 1];
        const short* p0 = proj_b + (size_t)s0 * (4 * F) + f;
        const short* p1 = proj_b + (size_t)s1 * (4 * F) + f;
        acc += a0.x * b2f(p0[0]) + a0.y * b2f(p0[F])
             + a0.z * b2f(p0[2 * F]) + a0.w * b2f(p0[3 * F]);
        acc += a1.x * b2f(p1[0]) + a1.y * b2f(p1[F])
             + a1.z * b2f(p1[2 * F]) + a1.w * b2f(p1[3 * F]);
    }
    if (sl < end) {
        const float4 a0 = *(const float4*)(attnT + 4 * (size_t)sl);
        const int s0 = csr_srcT[sl];
        const short* p0 = proj_b + (size_t)s0 * (4 * F) + f;
        acc += a0.x * b2f(p0[0]) + a0.y * b2f(p0[F])
             + a0.z * b2f(p0[2 * F]) + a0.w * b2f(p0[3 * F]);
    }
    const int o = node * F + f;
    aggb[o] = f2b(acc * 0.25f + b2f(x_pb[o]) + bias[f]);
}

// ---------------------------------------------------------------------------
extern "C" void kernel_launch(void* const* d_in, const int* in_sizes, int n_in,
                              void* d_out, int out_size, void* d_ws, size_t ws_size,
                              hipStream_t stream)
{
    const float* rna   = (const float*)d_in[0];    // [N,128]
    const float* prot  = (const float*)d_in[1];    // [N,32]
    const int*   ei    = (const int*)  d_in[2];    // [2,E]
    const float* Wgp   = (const float*)d_in[3];    // [128,64]
    const float* bgp   = (const float*)d_in[4];
    const float* Wgr   = (const float*)d_in[5];    // [64,128]
    const float* bgr   = (const float*)d_in[6];
    const float* Wg    = (const float*)d_in[7];    // [64,256]
    const float* ags   = (const float*)d_in[8];    // [4,64]
    const float* agt   = (const float*)d_in[9];
    const float* bg    = (const float*)d_in[10];   // [64]
    const float* Wcp   = (const float*)d_in[11];   // [160,96]
    const float* bcp   = (const float*)d_in[12];
    const float* Wcr   = (const float*)d_in[13];   // [96,160]
    const float* bcr   = (const float*)d_in[14];
    const float* Wc    = (const float*)d_in[15];   // [96,384]
    const float* acs   = (const float*)d_in[16];   // [4,96]
    const float* act   = (const float*)d_in[17];
    const float* bc    = (const float*)d_in[18];   // [96]

    float* out_gat   = (float*)d_out;              // [N,128]
    float* out_cross = out_gat + (size_t)NN * 128; // [N,160]

    // ---- workspace layout ----
    float* attnT  = (float*)d_ws;                  // E*4 f32 (trg-slot order)
    float* ssrc   = attnT + (size_t)NE * 4;        // N*4 f32
    float* strg   = ssrc + (size_t)NN * 4;         // N*4 f32
    short* proj_b = (short*)(strg + (size_t)NN * 4);// N*384 bf16
    short* cb     = proj_b + (size_t)NN * 384;     // N*160 bf16
    short* x_pb   = cb    + (size_t)NN * 160;      // N*96 bf16
    short* aggb   = x_pb  + (size_t)NN * 96;       // N*96 bf16
    short* wt_gp  = aggb  + (size_t)NN * 96;       // [64,128]
    short* wt_g   = wt_gp + 128 * 64;              // [256,64]
    short* wt_gr  = wt_g  + 64 * 256;              // [128,64]
    short* wt_cp  = wt_gr + 64 * 128;              // [96,160]
    short* wt_c   = wt_cp + 160 * 96;              // [384,96]
    short* wt_cr  = wt_c  + 96 * 384;              // [160,96]
    int*   deg_t  = (int*)(wt_cr + 96 * 160);      // N
    int*   deg_s  = deg_t  + NN;                   // N (adjacent: one zero pass)
    int*   cursor_t = deg_s  + NN;                 // N
    int*   cursor_s = cursor_t + NN;               // N
    int*   rowptr_t = cursor_s + NN;               // N+1
    int*   rowptr_s = rowptr_t + NN + 1;           // N+1
    int*   csr_srcT = rowptr_s + NN + 1;           // E (src per trg-slot)
    int*   csr_trgS = csr_srcT + NE;               // E (trg per src-slot)
    int*   map_s2t  = csr_trgS + NE;               // E (src-slot -> trg-slot)

    // ---- one-time converts + dual CSR build ----
    concat_kernel<<<(NN * 40 + 255) / 256, 256, 0, stream>>>(rna, prot, cb);
    wt_all_kernel<<<dim3(144, 6), 256, 0, stream>>>(Wgp, Wg, Wgr, Wcp, Wc, Wcr,
                                                    wt_gp, wt_g, wt_gr, wt_cp, wt_c, wt_cr);
    zero_kernel<<<(2 * NN) / (256 * 4), 256, 0, stream>>>((int4*)deg_t);
    hist_dual<<<NE / 256, 256, 0, stream>>>(ei, deg_t, deg_s);
    scan_dual<<<2, 1024, 0, stream>>>(deg_t, rowptr_t, cursor_t, deg_s, rowptr_s, cursor_s);
    scatter_dual<<<NE / 256, 256, 0, stream>>>(ei, cursor_t, csr_srcT,
                                               cursor_s, csr_trgS, map_s2t);

    // ======================= GAT path (F=64, softmax on trg) ================
    mfma_gemm<128, 160,  64, 128,  64, true ><<<dim3(256, 1), 256, 0, stream>>>(cb,   wt_gp, bgp, nullptr, x_pb);
    mfma_gemm< 64,  64, 256, 128, 128, true ><<<dim3(256, 2), 256, 0, stream>>>(x_pb, wt_g,  nullptr, nullptr, proj_b);
    scores_proj<64><<<(NN * HH) / 256, 256, 0, stream>>>(proj_b, ags, agt, ssrc, strg);
    gat_denattn<<<NN / 256, 256, 0, stream>>>(rowptr_t, csr_srcT, ssrc, strg, attnT);
    aggregate_lean<64, 4><<<NN / 4, dim3(64, 4), 0, stream>>>(
        rowptr_t, csr_srcT, attnT, proj_b, x_pb, bg, aggb);
    mfma_gemm< 64,  64, 128, 128, 128, false><<<dim3(256, 1), 256, 0, stream>>>(aggb, wt_gr, bgr, out_gat, nullptr);

    // ====================== Cross path (F=96, softmax on src) ===============
    mfma_gemm<160, 160,  96,  64,  96, true ><<<dim3(512, 1), 256, 0, stream>>>(cb,   wt_cp, bcp, nullptr, x_pb);
    mfma_gemm< 96,  96, 384, 128, 128, true ><<<dim3(256, 3), 256, 0, stream>>>(x_pb, wt_c,  nullptr, nullptr, proj_b);
    scores_proj<96><<<(NN * HH) / 256, 256, 0, stream>>>(proj_b, acs, act, ssrc, strg);
    cross_denattn<<<NN / 256, 256, 0, stream>>>(rowptr_s, csr_trgS, map_s2t, ssrc, strg, attnT);
    aggregate_lean<96, 2><<<NN / 2, dim3(96, 2), 0, stream>>>(
        rowptr_t, csr_srcT, attnT, proj_b, x_pb, bc, aggb);
    mfma_gemm< 96,  96, 160, 128,  80, false><<<dim3(256, 2), 256, 0, stream>>>(aggb, wt_cr, bcr, out_cross, nullptr);
}

// Round 9
// 178.070 us; speedup vs baseline: 1.9169x; 1.1605x over previous
//
#include <hip/hip_runtime.h>
#include <hip/hip_bf16.h>

#define NN 32768      // nodes
#define NE 131072     // edges
#define HH 4          // heads

constexpr float kLrelu = 0.2f;

using bf16x8 = __attribute__((ext_vector_type(8))) __bf16;
using f32x4  = __attribute__((ext_vector_type(4))) float;

__device__ inline short f2b(float f) {
    __hip_bfloat16 h = __float2bfloat16(f);          // RTNE
    return __builtin_bit_cast(short, h);
}
__device__ inline float b2f(short s) {
    __hip_bfloat16 h = __builtin_bit_cast(__hip_bfloat16, s);
    return __bfloat162float(h);
}
__device__ inline float blo(int u) {                 // bf16 in bits[15:0]
    return __builtin_bit_cast(float, (int)(u << 16));
}
__device__ inline float bhi(int u) {                 // bf16 in bits[31:16]
    return __builtin_bit_cast(float, (int)(u & 0xffff0000));
}
__device__ inline float lrexp(float x) {             // exp(leaky_relu(x))
    return __expf(x > 0.f ? x : kLrelu * x);
}

// ---------------------------------------------------------------------------
// LDS-staged bf16 MFMA GEMM (round-7-proven structure, retiled for occupancy:
// BM in {32,64} -> 1024-1536 blocks, LDS 18-47KB -> 3-6 blocks/CU).
// ---------------------------------------------------------------------------
template<int K, int LDA, int OUTN, int BM, int BN, bool BF16OUT>
__global__ __launch_bounds__(256) void mfma_gemm(
    const short* __restrict__ A, const short* __restrict__ Wt,
    const float* __restrict__ bias,
    float* __restrict__ Cf, short* __restrict__ Cb)
{
    constexpr int KP    = K + 8;           // padded LDS row (shorts)
    constexpr int WM    = BM / 32;         // waves along rows (1 or 2)
    constexpr int WN    = 4 / WM;          // waves along cols
    constexpr int WBN   = BN / WN;         // cols per wave (mult of 16)
    constexpr int CF    = WBN / 16;        // col frags per wave
    constexpr int CPR   = K / 8;           // 16B chunks per K-row
    constexpr int TOT   = (BM + BN) * KP;  // total LDS shorts
    constexpr int SLICE = TOT / 4;         // per-wave epilogue slice (shorts)

    __shared__ short lds[TOT];
    short* As = lds;
    short* Bs = lds + BM * KP;

    const int tid  = threadIdx.x;
    const int wave = tid >> 6;
    const int lane = tid & 63;
    const int lr   = lane & 15;
    const int kb   = lane >> 4;            // 0..3
    const int wm   = wave % WM;
    const int wn   = wave / WM;
    const int row0 = blockIdx.x * BM;
    const int col0 = blockIdx.y * BN;

    #pragma unroll
    for (int g = tid; g < BM * CPR; g += 256) {
        int r = g / CPR, c = g - r * CPR;
        bf16x8 v = *(const bf16x8*)(A + (size_t)(row0 + r) * LDA + c * 8);
        *(bf16x8*)(As + r * KP + c * 8) = v;
    }
    #pragma unroll
    for (int g = tid; g < BN * CPR; g += 256) {
        int r = g / CPR, c = g - r * CPR;
        bf16x8 v = *(const bf16x8*)(Wt + (size_t)(col0 + r) * K + c * 8);
        *(bf16x8*)(Bs + r * KP + c * 8) = v;
    }
    __syncthreads();

    f32x4 acc[2][CF] = {};
    #pragma unroll
    for (int k0 = 0; k0 < K; k0 += 32) {
        bf16x8 af0 = *(const bf16x8*)(As + (wm * 32 + lr     ) * KP + k0 + kb * 8);
        bf16x8 af1 = *(const bf16x8*)(As + (wm * 32 + lr + 16) * KP + k0 + kb * 8);
        #pragma unroll
        for (int cf = 0; cf < CF; ++cf) {
            bf16x8 bv = *(const bf16x8*)(Bs + (wn * WBN + cf * 16 + lr) * KP + k0 + kb * 8);
            acc[0][cf] = __builtin_amdgcn_mfma_f32_16x16x32_bf16(af0, bv, acc[0][cf], 0, 0, 0);
            acc[1][cf] = __builtin_amdgcn_mfma_f32_16x16x32_bf16(af1, bv, acc[1][cf], 0, 0, 0);
        }
    }

    #pragma unroll
    for (int mf = 0; mf < 2; ++mf) {
        __syncthreads();
        if constexpr (BF16OUT) {
            constexpr int LEP = WBN + 8;
            short* ep = lds + wave * SLICE;
            #pragma unroll
            for (int cf = 0; cf < CF; ++cf) {
                const int c  = cf * 16 + lr;
                const float bv = bias ? bias[col0 + wn * WBN + c] : 0.0f;
                #pragma unroll
                for (int j = 0; j < 4; ++j)
                    ep[(kb * 4 + j) * LEP + c] = f2b(acc[mf][cf][j] + bv);
            }
            __syncthreads();
            constexpr int CROW = WBN / 8;
            for (int g = lane; g < 16 * CROW; g += 64) {
                int r = g / CROW, cc = g - r * CROW;
                bf16x8 v = *(const bf16x8*)(ep + r * LEP + cc * 8);
                *(bf16x8*)(Cb + (size_t)(row0 + wm * 32 + mf * 16 + r) * OUTN
                              + col0 + wn * WBN + cc * 8) = v;
            }
        } else {
            constexpr int LEPF = WBN + 4;
            float* epf = (float*)(lds + wave * SLICE);
            #pragma unroll
            for (int cf = 0; cf < CF; ++cf) {
                const int c  = cf * 16 + lr;
                const float bv = bias ? bias[col0 + wn * WBN + c] : 0.0f;
                #pragma unroll
                for (int j = 0; j < 4; ++j)
                    epf[(kb * 4 + j) * LEPF + c] = acc[mf][cf][j] + bv;
            }
            __syncthreads();
            constexpr int CROWF = WBN / 4;
            for (int g = lane; g < 16 * CROWF; g += 64) {
                int r = g / CROWF, cc = g - r * CROWF;
                float4 v = *(const float4*)(epf + r * LEPF + cc * 4);
                *(float4*)(Cf + (size_t)(row0 + wm * 32 + mf * 16 + r) * OUTN
                              + col0 + wn * WBN + cc * 4) = v;
            }
        }
    }
}

// ---------------------------------------------------------------------------
// Node scores from stored proj: s[n,h] = sum_f proj[n,h,f]*a[h,f].
// ---------------------------------------------------------------------------
template<int F>
__global__ __launch_bounds__(256) void scores_proj(
    const short* __restrict__ proj_b,
    const float* __restrict__ a_src, const float* __restrict__ a_trg,
    float* __restrict__ ssrc, float* __restrict__ strg)
{
    int t = blockIdx.x * 256 + threadIdx.x;
    if (t >= NN * HH) return;
    int n = t >> 2, h = t & 3;
    const int4* p = (const int4*)(proj_b + (size_t)n * (4 * F) + h * F);
    const float* as = a_src + h * F;
    const float* at = a_trg + h * F;
    float ss = 0.f, st = 0.f;
    #pragma unroll
    for (int c = 0; c < F / 8; ++c) {
        int4 v = p[c];
        int u[4] = { v.x, v.y, v.z, v.w };
        #pragma unroll
        for (int q = 0; q < 4; ++q) {
            float x0 = blo(u[q]), x1 = bhi(u[q]);
            ss += x0 * as[c * 8 + 2 * q] + x1 * as[c * 8 + 2 * q + 1];
            st += x0 * at[c * 8 + 2 * q] + x1 * at[c * 8 + 2 * q + 1];
        }
    }
    ssrc[t] = ss;
    strg[t] = st;
}

// ---------------------------------------------------------------------------
// Fused prologue: concat (blocks 0..5119), 6 weight transposes (5120..5983),
// zero deg arrays (5984..6047). One launch replaces three.
// ---------------------------------------------------------------------------
__global__ __launch_bounds__(256) void prep_kernel(
    const float* __restrict__ rna, const float* __restrict__ prot,
    short* __restrict__ cb,
    const float* W0, const float* W1, const float* W2,
    const float* W3, const float* W4, const float* W5,
    short* T0, short* T1, short* T2, short* T3, short* T4, short* T5,
    int4* __restrict__ zero_p)
{
    const int bid = blockIdx.x;
    if (bid < 5120) {                                  // concat
        int t = bid * 256 + threadIdx.x;
        int n = t / 40, j = (t - n * 40) * 4;
        float4 v = (j < 128) ? *(const float4*)(rna  + (size_t)n * 128 + j)
                             : *(const float4*)(prot + (size_t)n * 32 + (j - 128));
        short4 o = { f2b(v.x), f2b(v.y), f2b(v.z), f2b(v.w) };
        *(short4*)(cb + (size_t)n * 160 + j) = o;
    } else if (bid < 5984) {                           // weight transposes
        int idx = bid - 5120;
        int wsel = idx / 144, sub = idx - wsel * 144;
        int K, N; const float* W; short* T;
        switch (wsel) {
            case 0: K = 128; N =  64; W = W0; T = T0; break;
            case 1: K =  64; N = 256; W = W1; T = T1; break;
            case 2: K =  64; N = 128; W = W2; T = T2; break;
            case 3: K = 160; N =  96; W = W3; T = T3; break;
            case 4: K =  96; N = 384; W = W4; T = T4; break;
            default:K =  96; N = 160; W = W5; T = T5; break;
        }
        int t = sub * 256 + threadIdx.x;
        if (t >= K * N) return;
        int n = t / K, k = t - n * K;
        T[t] = f2b(W[(size_t)k * N + n]);
    } else {                                           // zero deg_t+deg_s
        zero_p[(bid - 5984) * 256 + threadIdx.x] = make_int4(0, 0, 0, 0);
    }
}

// ---------------------------------------------------------------------------
// Dual CSR build: trg-CSR (src per slot, for aggregation) and src-CSR
// (trg per slot, for cross denominators).
// ---------------------------------------------------------------------------
__global__ __launch_bounds__(256) void hist_dual(const int* __restrict__ ei,
                                                 int* __restrict__ deg_t,
                                                 int* __restrict__ deg_s)
{
    int e = blockIdx.x * 256 + threadIdx.x;
    if (e >= NE) return;
    atomicAdd(&deg_s[ei[e]], 1);
    atomicAdd(&deg_t[ei[NE + e]], 1);
}

__global__ __launch_bounds__(1024) void scan_dual(
    const int* __restrict__ deg_t, int* __restrict__ rowptr_t, int* __restrict__ cursor_t,
    const int* __restrict__ deg_s, int* __restrict__ rowptr_s, int* __restrict__ cursor_s)
{
    const int* deg    = blockIdx.x ? deg_s    : deg_t;
    int*       rowptr = blockIdx.x ? rowptr_s : rowptr_t;
    int*       cursor = blockIdx.x ? cursor_s : cursor_t;
    __shared__ int sums[1024];
    const int t = threadIdx.x;
    const int base = t * 32;
    int local[32];
    int s = 0;
    #pragma unroll
    for (int i = 0; i < 32; ++i) { local[i] = s; s += deg[base + i]; }
    sums[t] = s;
    __syncthreads();
    for (int off = 1; off < 1024; off <<= 1) {
        int v = (t >= off) ? sums[t - off] : 0;
        __syncthreads();
        sums[t] += v;
        __syncthreads();
    }
    const int prev = (t == 0) ? 0 : sums[t - 1];
    #pragma unroll
    for (int i = 0; i < 32; ++i) {
        rowptr[base + i] = prev + local[i];
        cursor[base + i] = prev + local[i];
    }
    if (t == 1023) rowptr[NN] = prev + s;
}

__global__ __launch_bounds__(256) void scatter_dual(
    const int* __restrict__ ei,
    int* __restrict__ cursor_t, int* __restrict__ csr_srcT,
    int* __restrict__ cursor_s, int* __restrict__ csr_trgS)
{
    int e = blockIdx.x * 256 + threadIdx.x;
    if (e >= NE) return;
    int s = ei[e], t = ei[NE + e];
    int st = atomicAdd(&cursor_t[t], 1);
    csr_srcT[st] = s;
    int ss = atomicAdd(&cursor_s[s], 1);
    csr_trgS[ss] = t;
}

// ---------------------------------------------------------------------------
// Cross denominator RECIPROCALS via src-CSR: recip[n][h] =
// 1/(sum_{e:src=n} exp(lrelu(ssrc[n]+strg[trg])) + eps). Division happens
// N*4 times here instead of E*4 times in the aggregate.
// ---------------------------------------------------------------------------
__global__ __launch_bounds__(256) void den_src_kernel(
    const int* __restrict__ rowptr_s, const int* __restrict__ csr_trgS,
    const float* __restrict__ ssrc, const float* __restrict__ strg,
    float* __restrict__ recip)
{
    int n = blockIdx.x * 256 + threadIdx.x;
    if (n >= NN) return;
    const int beg = rowptr_s[n], end = rowptr_s[n + 1];
    const float4 sv = *(const float4*)(ssrc + 4 * (size_t)n);
    float d0 = 0.f, d1 = 0.f, d2 = 0.f, d3 = 0.f;
    for (int sl = beg; sl < end; ++sl) {
        const int t = csr_trgS[sl];
        const float4 tv = *(const float4*)(strg + 4 * (size_t)t);
        d0 += lrexp(sv.x + tv.x); d1 += lrexp(sv.y + tv.y);
        d2 += lrexp(sv.z + tv.z); d3 += lrexp(sv.w + tv.w);
    }
    *(float4*)(recip + 4 * (size_t)n) =
        make_float4(1.f / (d0 + 1e-16f), 1.f / (d1 + 1e-16f),
                    1.f / (d2 + 1e-16f), 1.f / (d3 + 1e-16f));
}

// ---------------------------------------------------------------------------
// FUSED softmax+aggregate over trg-CSR (single edge pass, no attn buffer).
// Thread = (2 features, node). Per edge: gather ssrc[s] (16B bcast),
// exp inline; GAT (GROUP_SRC=false): per-head accumulators + local denom,
// divide once per node at the end (linearity of the aggregation).
// Cross (GROUP_SRC=true): multiply by precomputed recip[s].
// proj gathered as int (2 bf16) -> half the VMEM instructions.
// Fused mean+skip+bias -> bf16 short2 store.
// ---------------------------------------------------------------------------
template<int F, int NPB, bool GROUP_SRC>
__global__ __launch_bounds__((F / 2) * NPB) void aggregate_fused(
    const int* __restrict__ rowptr_t, const int* __restrict__ csr_srcT,
    const float* __restrict__ ssrc, const float* __restrict__ strg,
    const float* __restrict__ recip,
    const short* __restrict__ proj_b,
    const short* __restrict__ x_pb, const float* __restrict__ bias,
    short* __restrict__ aggb)
{
    const int f2   = threadIdx.x * 2;
    const int node = blockIdx.x * NPB + threadIdx.y;
    const int beg  = rowptr_t[node], end = rowptr_t[node + 1];
    const float4 stv = *(const float4*)(strg + 4 * (size_t)node);

    float a0 = 0.f, a1 = 0.f;                       // final 2-feature accums
    float h0l = 0.f, h1l = 0.f, h2l = 0.f, h3l = 0.f;   // GAT per-head lo
    float h0h = 0.f, h1h = 0.f, h2h = 0.f, h3h = 0.f;   // GAT per-head hi
    float d0 = 0.f, d1 = 0.f, d2 = 0.f, d3 = 0.f;       // GAT denoms

    #pragma unroll 2
    for (int sl = beg; sl < end; ++sl) {
        const int s = csr_srcT[sl];
        const float4 sv = *(const float4*)(ssrc + 4 * (size_t)s);
        float e0 = lrexp(sv.x + stv.x);
        float e1 = lrexp(sv.y + stv.y);
        float e2 = lrexp(sv.z + stv.z);
        float e3 = lrexp(sv.w + stv.w);
        const short* p = proj_b + (size_t)s * (4 * F) + f2;
        const int u0 = *(const int*)(p);
        const int u1 = *(const int*)(p + F);
        const int u2 = *(const int*)(p + 2 * F);
        const int u3 = *(const int*)(p + 3 * F);
        if constexpr (GROUP_SRC) {
            const float4 rc = *(const float4*)(recip + 4 * (size_t)s);
            e0 *= rc.x; e1 *= rc.y; e2 *= rc.z; e3 *= rc.w;
            a0 += e0 * blo(u0) + e1 * blo(u1) + e2 * blo(u2) + e3 * blo(u3);
            a1 += e0 * bhi(u0) + e1 * bhi(u1) + e2 * bhi(u2) + e3 * bhi(u3);
        } else {
            d0 += e0; d1 += e1; d2 += e2; d3 += e3;
            h0l += e0 * blo(u0); h0h += e0 * bhi(u0);
            h1l += e1 * blo(u1); h1h += e1 * bhi(u1);
            h2l += e2 * blo(u2); h2h += e2 * bhi(u2);
            h3l += e3 * blo(u3); h3h += e3 * bhi(u3);
        }
    }
    if constexpr (!GROUP_SRC) {
        const float r0 = 1.f / (d0 + 1e-16f), r1 = 1.f / (d1 + 1e-16f);
        const float r2 = 1.f / (d2 + 1e-16f), r3 = 1.f / (d3 + 1e-16f);
        a0 = h0l * r0 + h1l * r1 + h2l * r2 + h3l * r3;
        a1 = h0h * r0 + h1h * r1 + h2h * r2 + h3h * r3;
    }
    const int o = node * F + f2;
    const int ux = *(const int*)(x_pb + o);
    const float v0 = a0 * 0.25f + blo(ux) + bias[f2];
    const float v1 = a1 * 0.25f + bhi(ux) + bias[f2 + 1];
    const int packed = (f2b(v0) & 0xffff) | ((int)f2b(v1) << 16);
    *(int*)(aggb + o) = packed;
}

// ---------------------------------------------------------------------------
extern "C" void kernel_launch(void* const* d_in, const int* in_sizes, int n_in,
                              void* d_out, int out_size, void* d_ws, size_t ws_size,
                              hipStream_t stream)
{
    const float* rna   = (const float*)d_in[0];    // [N,128]
    const float* prot  = (const float*)d_in[1];    // [N,32]
    const int*   ei    = (const int*)  d_in[2];    // [2,E]
    const float* Wgp   = (const float*)d_in[3];    // [128,64]
    const float* bgp   = (const float*)d_in[4];
    const float* Wgr   = (const float*)d_in[5];    // [64,128]
    const float* bgr   = (const float*)d_in[6];
    const float* Wg    = (const float*)d_in[7];    // [64,256]
    const float* ags   = (const float*)d_in[8];    // [4,64]
    const float* agt   = (const float*)d_in[9];
    const float* bg    = (const float*)d_in[10];   // [64]
    const float* Wcp   = (const float*)d_in[11];   // [160,96]
    const float* bcp   = (const float*)d_in[12];
    const float* Wcr   = (const float*)d_in[13];   // [96,160]
    const float* bcr   = (const float*)d_in[14];
    const float* Wc    = (const float*)d_in[15];   // [96,384]
    const float* acs   = (const float*)d_in[16];   // [4,96]
    const float* act   = (const float*)d_in[17];
    const float* bc    = (const float*)d_in[18];   // [96]

    float* out_gat   = (float*)d_out;              // [N,128]
    float* out_cross = out_gat + (size_t)NN * 128; // [N,160]

    // ---- workspace layout ----
    float* ssrc   = (float*)d_ws;                  // N*4 f32
    float* strg   = ssrc + (size_t)NN * 4;         // N*4 f32
    float* recip  = strg + (size_t)NN * 4;         // N*4 f32
    short* proj_b = (short*)(recip + (size_t)NN * 4); // N*384 bf16
    short* cb     = proj_b + (size_t)NN * 384;     // N*160 bf16
    short* x_pb   = cb    + (size_t)NN * 160;      // N*96 bf16
    short* aggb   = x_pb  + (size_t)NN * 96;       // N*96 bf16
    short* wt_gp  = aggb  + (size_t)NN * 96;       // [64,128]
    short* wt_g   = wt_gp + 128 * 64;              // [256,64]
    short* wt_gr  = wt_g  + 64 * 256;              // [128,64]
    short* wt_cp  = wt_gr + 64 * 128;              // [96,160]
    short* wt_c   = wt_cp + 160 * 96;              // [384,96]
    short* wt_cr  = wt_c  + 96 * 384;              // [160,96]
    int*   deg_t  = (int*)(wt_cr + 96 * 160);      // N
    int*   deg_s  = deg_t  + NN;                   // N (adjacent: one zero pass)
    int*   cursor_t = deg_s  + NN;                 // N
    int*   cursor_s = cursor_t + NN;               // N
    int*   rowptr_t = cursor_s + NN;               // N+1
    int*   rowptr_s = rowptr_t + NN + 1;           // N+1
    int*   csr_srcT = rowptr_s + NN + 1;           // E (src per trg-slot)
    int*   csr_trgS = csr_srcT + NE;               // E (trg per src-slot)

    // ---- prologue: concat + weight transposes + zero, then CSR build ----
    prep_kernel<<<6048, 256, 0, stream>>>(rna, prot, cb,
                                          Wgp, Wg, Wgr, Wcp, Wc, Wcr,
                                          wt_gp, wt_g, wt_gr, wt_cp, wt_c, wt_cr,
                                          (int4*)deg_t);
    hist_dual<<<NE / 256, 256, 0, stream>>>(ei, deg_t, deg_s);
    scan_dual<<<2, 1024, 0, stream>>>(deg_t, rowptr_t, cursor_t, deg_s, rowptr_s, cursor_s);
    scatter_dual<<<NE / 256, 256, 0, stream>>>(ei, cursor_t, csr_srcT, cursor_s, csr_trgS);

    // ======================= GAT path (F=64, softmax on trg) ================
    mfma_gemm<128, 160,  64, 32,  64, true ><<<dim3(1024, 1), 256, 0, stream>>>(cb,   wt_gp, bgp, nullptr, x_pb);
    mfma_gemm< 64,  64, 256, 64, 128, true ><<<dim3( 512, 2), 256, 0, stream>>>(x_pb, wt_g,  nullptr, nullptr, proj_b);
    scores_proj<64><<<(NN * HH) / 256, 256, 0, stream>>>(proj_b, ags, agt, ssrc, strg);
    aggregate_fused<64, 8, false><<<NN / 8, dim3(32, 8), 0, stream>>>(
        rowptr_t, csr_srcT, ssrc, strg, nullptr, proj_b, x_pb, bg, aggb);
    mfma_gemm< 64,  64, 128, 64,  64, false><<<dim3( 512, 2), 256, 0, stream>>>(aggb, wt_gr, bgr, out_gat, nullptr);

    // ====================== Cross path (F=96, softmax on src) ===============
    mfma_gemm<160, 160,  96, 64,  96, true ><<<dim3( 512, 1), 256, 0, stream>>>(cb,   wt_cp, bcp, nullptr, x_pb);
    mfma_gemm< 96,  96, 384, 64, 128, true ><<<dim3( 512, 3), 256, 0, stream>>>(x_pb, wt_c,  nullptr, nullptr, proj_b);
    scores_proj<96><<<(NN * HH) / 256, 256, 0, stream>>>(proj_b, acs, act, ssrc, strg);
    den_src_kernel<<<NN / 256, 256, 0, stream>>>(rowptr_s, csr_trgS, ssrc, strg, recip);
    aggregate_fused<96, 8, true><<<NN / 8, dim3(48, 8), 0, stream>>>(
        rowptr_t, csr_srcT, ssrc, strg, recip, proj_b, x_pb, bc, aggb);
    mfma_gemm< 96,  96, 160, 64, 160, false><<<dim3( 512, 1), 256, 0, stream>>>(aggb, wt_cr, bcr, out_cross, nullptr);
}